// Round 1
// 693.070 us; speedup vs baseline: 1.0061x; 1.0061x over previous
//
#include <hip/hip_runtime.h>
#include <stdint.h>

typedef unsigned int uint;
typedef unsigned short ushort;

typedef __attribute__((ext_vector_type(8))) short bf16x8;   // 8 bf16 = 4 VGPRs
typedef __attribute__((ext_vector_type(16))) float f32x16;  // MFMA 32x32 acc
typedef __attribute__((ext_vector_type(4))) int   i32x4;    // CSR record
typedef __attribute__((ext_vector_type(4))) float f32x4;

__device__ inline float bflo(uint u) {
    union { uint x; float f; } z; z.x = u << 16; return z.f;
}
__device__ inline float bfhi(uint u) {
    union { uint x; float f; } z; z.x = u & 0xffff0000u; return z.f;
}
__device__ inline ushort f2bf(float f) {
    union { float f; uint u; } x; x.f = f;
    uint r = (x.u + 0x7fffu + ((x.u >> 16) & 1u)) >> 16;
    return (ushort)r;
}

// ---------------------------------------------------------------------------
// pack_x: x (fp32 row-major) -> bf16 fragment-ordered tiles:
//   xfrag chunk index o = tile*2048 + kb*128 + m   (chunk = 16B = 8 bf16)
//   holds x[tile*128+m][kb*8 .. kb*8+8), zero-padded past n rows.
// ---------------------------------------------------------------------------
__global__ __launch_bounds__(256) void pack_x(const float* __restrict__ x,
                                              uint4* __restrict__ xfrag,
                                              int n, int nchunks)
{
    int o = blockIdx.x * 256 + threadIdx.x;
    if (o >= nchunks) return;
    int m    = o & 127;
    int kb   = (o >> 7) & 15;
    int tile = o >> 11;
    int row  = tile * 128 + m;
    float4 lo = make_float4(0.f, 0.f, 0.f, 0.f);
    float4 hi = make_float4(0.f, 0.f, 0.f, 0.f);
    if (row < n) {
        lo = *(const float4*)&x[(size_t)row * 128 + kb * 8];
        hi = *(const float4*)&x[(size_t)row * 128 + kb * 8 + 4];
    }
    uint4 ov;
    ov.x = (uint)f2bf(lo.x) | ((uint)f2bf(lo.y) << 16);
    ov.y = (uint)f2bf(lo.z) | ((uint)f2bf(lo.w) << 16);
    ov.z = (uint)f2bf(hi.x) | ((uint)f2bf(hi.y) << 16);
    ov.w = (uint)f2bf(hi.z) | ((uint)f2bf(hi.w) << 16);
    xfrag[o] = ov;
}

// ---------------------------------------------------------------------------
// pack_w: W_j (fp32 [K=128][N=128] row-major) -> bf16 B-fragment order.
// ---------------------------------------------------------------------------
__global__ __launch_bounds__(256) void pack_w(
    const float* __restrict__ W0, const float* __restrict__ W1,
    const float* __restrict__ W2, const float* __restrict__ W3,
    uint4* __restrict__ wfrag)
{
    int o = blockIdx.x * 256 + threadIdx.x;   // 4*16*128 = 8192 chunks
    if (o >= 8192) return;
    int nn = o & 127;
    int kb = (o >> 7) & 15;
    int j  = o >> 11;
    const float* W = (j == 0) ? W0 : (j == 1) ? W1 : (j == 2) ? W2 : W3;
    float v[8];
    #pragma unroll
    for (int i = 0; i < 8; ++i) v[i] = W[(size_t)(kb * 8 + i) * 128 + nn];
    uint4 ov;
    ov.x = (uint)f2bf(v[0]) | ((uint)f2bf(v[1]) << 16);
    ov.y = (uint)f2bf(v[2]) | ((uint)f2bf(v[3]) << 16);
    ov.z = (uint)f2bf(v[4]) | ((uint)f2bf(v[5]) << 16);
    ov.w = (uint)f2bf(v[6]) | ((uint)f2bf(v[7]) << 16);
    wfrag[o] = ov;
}

// ---------------------------------------------------------------------------
// lin_mfma: per block, 128 rows x all 4 weight matrices (512 cols), K=128.
// v_mfma_f32_32x32x16_bf16; C/D: col=lane&31, row=(reg&3)+8*(reg>>2)+4*(lane>>5).
// Outputs bf16-pair packed: q [n][64], kv [n][128] (k 0..63 | v 64..127),
// skip [n][64].
// ---------------------------------------------------------------------------
__global__ __launch_bounds__(256) void lin_mfma(
    const uint4* __restrict__ xfrag, const uint4* __restrict__ wfrag,
    const float* __restrict__ bq, const float* __restrict__ bk,
    const float* __restrict__ bv, const float* __restrict__ bs,
    uint* __restrict__ qout, uint* __restrict__ kvout, uint* __restrict__ sout,
    int n)
{
    const int tile = blockIdx.x;
    const int w  = threadIdx.x >> 6;
    const int l  = threadIdx.x & 63;
    const int lm = l & 31, lh = l >> 5;

    bf16x8 a[8];
    const uint4* ap = xfrag + (size_t)tile * 2048 + lh * 128 + w * 32 + lm;
    #pragma unroll
    for (int ks = 0; ks < 8; ++ks) a[ks] = *(const bf16x8*)(ap + ks * 256);

    const int rowbase = tile * 128 + w * 32 + 4 * lh;

    #pragma unroll
    for (int j = 0; j < 4; ++j) {
        const float* bias = (j == 0) ? bq : (j == 1) ? bk : (j == 2) ? bv : bs;
        uint* dst; int stride, cbase;
        if (j == 0)      { dst = qout;  stride = 64;  cbase = 0;  }
        else if (j == 1) { dst = kvout; stride = 128; cbase = 0;  }
        else if (j == 2) { dst = kvout; stride = 128; cbase = 64; }
        else             { dst = sout;  stride = 64;  cbase = 0;  }

        #pragma unroll
        for (int np = 0; np < 2; ++np) {       // ni pair {2np, 2np+1}
            const uint4* bp0 = wfrag + (size_t)j * 2048 + lh * 128 + (np * 2) * 32 + lm;
            f32x16 c0, c1;
            #pragma unroll
            for (int i = 0; i < 16; ++i) { c0[i] = 0.f; c1[i] = 0.f; }
            #pragma unroll
            for (int ks = 0; ks < 8; ++ks) {
                bf16x8 B0 = *(const bf16x8*)(bp0 + ks * 256);
                bf16x8 B1 = *(const bf16x8*)(bp0 + 32 + ks * 256);
                c0 = __builtin_amdgcn_mfma_f32_32x32x16_bf16(a[ks], B0, c0, 0, 0, 0);
                c1 = __builtin_amdgcn_mfma_f32_32x32x16_bf16(a[ks], B1, c1, 0, 0, 0);
            }
            #pragma unroll
            for (int t = 0; t < 2; ++t) {
                f32x16 cc = t ? c1 : c0;
                int gc = (np * 2 + t) * 32 + lm;
                float bl = bias[gc];
                #pragma unroll
                for (int r = 0; r < 16; ++r) {
                    float val = cc[r] + bl;
                    float partner = __shfl_xor(val, 1);
                    int gr = rowbase + (r & 3) + 8 * (r >> 2);
                    if (!(lm & 1) && gr < n) {
                        uint pk = (uint)f2bf(val) | ((uint)f2bf(partner) << 16);
                        dst[(size_t)gr * stride + cbase + (gc >> 1)] = pk;
                    }
                }
            }
        }
    }
}

// ---------------------------------------------------------------------------
// t[n,h,d] = sum_c We[d, h*32+c] * q[n, h*32+c]  — one wave per node,
// lane = h*16 + d. Output packed bf16 pairs: tb[n*32 + h*8 + d/2].
// (bf16 t: |t|~0.03, rounding ~1e-4 — negligible vs the bf16 q/k error floor)
// ---------------------------------------------------------------------------
__global__ __launch_bounds__(256) void t_kernel(const uint* __restrict__ qb,
                                                const float* __restrict__ We,
                                                uint* __restrict__ tb, int n)
{
    int wid = (blockIdx.x * blockDim.x + threadIdx.x) >> 6;
    int lane = threadIdx.x & 63;
    if (wid >= n) return;
    int h = lane >> 4, d = lane & 15;
    const uint* qp = qb + (size_t)wid * 64 + h * 16;
    const float* wp = We + (size_t)d * 128 + h * 32;
    float s = 0.f;
    #pragma unroll
    for (int j4 = 0; j4 < 16; j4 += 4) {
        uint4 u = *(const uint4*)(qp + j4);
        float4 wA = *(const float4*)&wp[2 * j4];
        float4 wB = *(const float4*)&wp[2 * j4 + 4];
        s += bflo(u.x) * wA.x + bfhi(u.x) * wA.y
           + bflo(u.y) * wA.z + bfhi(u.y) * wA.w
           + bflo(u.z) * wB.x + bfhi(u.z) * wB.y
           + bflo(u.w) * wB.z + bfhi(u.w) * wB.w;
    }
    float partner = __shfl_xor(s, 1);
    if (!(lane & 1)) {
        uint pk = (uint)f2bf(s) | ((uint)f2bf(partner) << 16);
        tb[(size_t)wid * 32 + (lane >> 1)] = pk;
    }
}

// ---------------------------------------------------------------------------
// CSR build: histogram -> scan (3 kernels) -> fused scatter+g
// ---------------------------------------------------------------------------
__global__ void hist_kernel(const int* __restrict__ rows, int* __restrict__ counts, int e)
{
    int i = blockIdx.x * blockDim.x + threadIdx.x;
    if (i < e) atomicAdd(&counts[rows[i]], 1);
}

__global__ __launch_bounds__(1024) void scan1_kernel(int* __restrict__ data,
                                                     int* __restrict__ bsum, int n)
{
    __shared__ int s[1024];
    int i = blockIdx.x * 1024 + threadIdx.x;
    int v = (i < n) ? data[i] : 0;
    s[threadIdx.x] = v;
    __syncthreads();
    for (int offd = 1; offd < 1024; offd <<= 1) {
        int add = (threadIdx.x >= offd) ? s[threadIdx.x - offd] : 0;
        __syncthreads();
        s[threadIdx.x] += add;
        __syncthreads();
    }
    if (i < n) data[i] = s[threadIdx.x];
    if (threadIdx.x == 1023) bsum[blockIdx.x] = s[1023];
}

__global__ __launch_bounds__(1024) void scan2_kernel(const int* __restrict__ bsum,
                                                     int* __restrict__ bofs, int nb)
{
    __shared__ int s[1024];
    int tid = threadIdx.x;
    int v = (tid < nb) ? bsum[tid] : 0;
    s[tid] = v;
    __syncthreads();
    for (int o = 1; o < 1024; o <<= 1) {
        int add = (tid >= o) ? s[tid - o] : 0;
        __syncthreads();
        s[tid] += add;
        __syncthreads();
    }
    if (tid < nb) bofs[tid] = s[tid] - v;
}

__global__ __launch_bounds__(1024) void scan3_kernel(const int* __restrict__ incl,
                                                     const int* __restrict__ bofs,
                                                     int* __restrict__ offsets, int n)
{
    int i = blockIdx.x * 1024 + threadIdx.x;
    if (i == 0) offsets[0] = 0;
    if (i < n) offsets[i + 1] = incl[i] + bofs[blockIdx.x];
}

// ---------------------------------------------------------------------------
// Fused scatter + edge-logit precompute. One thread per edge (edge order ->
// ea reads fully coalesced; t gather hits a 12.8 MB cache-resident buffer).
//   g[h] = sum_d ea[e,d] * t[row_e, h, d]       (the q·(ea@We) logit term)
// CSR record (16B): {src, eid, bf16pack(g0,g1), bf16pack(g2,g3)}.
// Regular (cached) store: csr footprint ~25.6 MB ~= aggregate L2, so lines
// accumulate multiple 16B writes before writeback.
// ---------------------------------------------------------------------------
__global__ __launch_bounds__(256) void scatter_g_kernel(
    const int* __restrict__ rows, const int* __restrict__ cols,
    const float* __restrict__ ea, const uint* __restrict__ tb,
    const int* __restrict__ offsets, int* __restrict__ cursor,
    i32x4* __restrict__ csr, int e)
{
    int i = blockIdx.x * blockDim.x + threadIdx.x;
    if (i >= e) return;
    int r = rows[i];
    int c = cols[i];
    const float* ep = &ea[(size_t)i * 16];
    float4 e0 = *(const float4*)(ep);
    float4 e1 = *(const float4*)(ep + 4);
    float4 e2 = *(const float4*)(ep + 8);
    float4 e3 = *(const float4*)(ep + 12);
    const uint* tp = tb + (size_t)r * 32;
    float g[4];
    #pragma unroll
    for (int h = 0; h < 4; ++h) {
        uint4 ua = *(const uint4*)(tp + h * 8);
        uint4 ub = *(const uint4*)(tp + h * 8 + 4);
        g[h] = e0.x * bflo(ua.x) + e0.y * bfhi(ua.x)
             + e0.z * bflo(ua.y) + e0.w * bfhi(ua.y)
             + e1.x * bflo(ua.z) + e1.y * bfhi(ua.z)
             + e1.z * bflo(ua.w) + e1.w * bfhi(ua.w)
             + e2.x * bflo(ub.x) + e2.y * bfhi(ub.x)
             + e2.z * bflo(ub.y) + e2.w * bfhi(ub.y)
             + e3.x * bflo(ub.z) + e3.y * bfhi(ub.z)
             + e3.z * bflo(ub.w) + e3.w * bfhi(ub.w);
    }
    int p = atomicAdd(&cursor[r], 1);
    int pos = offsets[r] + p;
    i32x4 rec;
    rec.x = c;
    rec.y = i;
    rec.z = (int)((uint)f2bf(g[0]) | ((uint)f2bf(g[1]) << 16));
    rec.w = (int)((uint)f2bf(g[2]) | ((uint)f2bf(g[3]) << 16));
    csr[pos] = rec;
}

// ---------------------------------------------------------------------------
// Aggregation: one wave per destination node, 4 edges in parallel.
// lane = es*16 + h*4 + cq. Lane owns channels c0 = h*32+cq*8 .. +8 of its
// edge slot. No edge_attr / t access — the ea@We logit term arrives as
// bf16 g embedded in the CSR record.
// ---------------------------------------------------------------------------
__global__ __launch_bounds__(256) void agg_kernel(
    const uint* __restrict__ qb, const uint* __restrict__ kv,
    const uint* __restrict__ sb, const i32x4* __restrict__ csr,
    const int* __restrict__ offsets, const float* __restrict__ Wbeta,
    float* __restrict__ out, int n)
{
    int wid = (blockIdx.x * blockDim.x + threadIdx.x) >> 6;
    int lane = threadIdx.x & 63;
    if (wid >= n) return;
    const int es = lane >> 4;
    const int h  = (lane >> 2) & 3;
    const int cq = lane & 3;
    const int c0 = h * 32 + cq * 8;

    uint4 uq = *(const uint4*)&qb[(size_t)wid * 64 + h * 16 + cq * 4];
    float qv[8] = { bflo(uq.x), bfhi(uq.x), bflo(uq.y), bfhi(uq.y),
                    bflo(uq.z), bfhi(uq.z), bflo(uq.w), bfhi(uq.w) };

    const int beg = offsets[wid], end = offsets[wid + 1];
    const float scale = 0.17677669529663687f;  // 1/sqrt(32)

    float denom = 0.f;
    float acc[8];
    #pragma unroll
    for (int j = 0; j < 8; ++j) acc[j] = 0.f;

    for (int i = beg; i < end; i += 4) {
        int idx = i + es;
        bool valid = idx < end;
        int cidx = valid ? idx : end - 1;
        i32x4 se = csr[cidx];
        uint gp = (h & 2) ? (uint)se.w : (uint)se.z;
        float gh = (h & 1) ? bfhi(gp) : bflo(gp);
        const uint* krow = kv + (size_t)se.x * 128 + h * 16 + cq * 4;
        uint4 kp = *(const uint4*)krow;
        uint4 vp = *(const uint4*)(krow + 64);

        float part = qv[0] * bflo(kp.x) + qv[1] * bfhi(kp.x)
                   + qv[2] * bflo(kp.y) + qv[3] * bfhi(kp.y)
                   + qv[4] * bflo(kp.z) + qv[5] * bfhi(kp.z)
                   + qv[6] * bflo(kp.w) + qv[7] * bfhi(kp.w);
        part += __shfl_xor(part, 1);
        part += __shfl_xor(part, 2);
        float p = valid ? __expf((part + gh) * scale) : 0.f;
        denom += p;
        acc[0] += p * bflo(vp.x); acc[1] += p * bfhi(vp.x);
        acc[2] += p * bflo(vp.y); acc[3] += p * bfhi(vp.y);
        acc[4] += p * bflo(vp.z); acc[5] += p * bfhi(vp.z);
        acc[6] += p * bflo(vp.w); acc[7] += p * bfhi(vp.w);
    }

    denom += __shfl_xor(denom, 16);
    denom += __shfl_xor(denom, 32);
    #pragma unroll
    for (int j = 0; j < 8; ++j) {
        acc[j] += __shfl_xor(acc[j], 16);
        acc[j] += __shfl_xor(acc[j], 32);
    }

    float inv = 1.f / (denom + 1e-16f);
    float o[8];
    #pragma unroll
    for (int j = 0; j < 8; ++j) o[j] = acc[j] * inv;

    uint4 us = *(const uint4*)&sb[(size_t)wid * 64 + h * 16 + cq * 4];
    float xsv[8] = { bflo(us.x), bfhi(us.x), bflo(us.y), bfhi(us.y),
                     bflo(us.z), bfhi(us.z), bflo(us.w), bfhi(us.w) };

    float bp = 0.f;
    #pragma unroll
    for (int j = 0; j < 8; ++j) {
        bp += o[j]   * Wbeta[c0 + j]
            + xsv[j] * Wbeta[128 + c0 + j]
            + (o[j] - xsv[j]) * Wbeta[256 + c0 + j];
    }
    bp += __shfl_xor(bp, 1);
    bp += __shfl_xor(bp, 2);
    bp += __shfl_xor(bp, 4);
    bp += __shfl_xor(bp, 8);
    float beta = 1.f / (1.f + __expf(-bp));

    if (es == 0) {
        float r[8];
        #pragma unroll
        for (int j = 0; j < 8; ++j) r[j] = beta * xsv[j] + (1.f - beta) * o[j];
        f32x4 r0 = { r[0], r[1], r[2], r[3] };
        f32x4 r1 = { r[4], r[5], r[6], r[7] };
        // out written once, full lines -> non-temporal keeps kv resident in L2
        __builtin_nontemporal_store(r0, (f32x4*)&out[(size_t)wid * 128 + c0]);
        __builtin_nontemporal_store(r1, (f32x4*)&out[(size_t)wid * 128 + c0 + 4]);
    }
}

// ---------------------------------------------------------------------------
extern "C" void kernel_launch(void* const* d_in, const int* in_sizes, int n_in,
                              void* d_out, int out_size, void* d_ws, size_t ws_size,
                              hipStream_t stream)
{
    const float* x     = (const float*)d_in[0];
    const float* ea    = (const float*)d_in[1];
    const int*   ei    = (const int*)d_in[2];   // [0:E)=row(dst), [E:2E)=col(src)
    const float* Wq    = (const float*)d_in[3];
    const float* bq    = (const float*)d_in[4];
    const float* Wk    = (const float*)d_in[5];
    const float* bk    = (const float*)d_in[6];
    const float* Wv    = (const float*)d_in[7];
    const float* bv    = (const float*)d_in[8];
    const float* We    = (const float*)d_in[9];
    const float* Wsk   = (const float*)d_in[10];
    const float* bsk   = (const float*)d_in[11];
    const float* Wbeta = (const float*)d_in[12];
    float* out = (float*)d_out;

    const int N = in_sizes[0] / 128;
    const int E = in_sizes[1] / 16;
    const int NT = (N + 127) / 128;         // 128-row tiles
    const int nchunks = NT * 2048;

    char* base = (char*)d_ws;
    size_t off = 0;
    auto alloc = [&](size_t bytes) -> void* {
        void* p = base + off;
        off += (bytes + 255) & ~(size_t)255;
        return p;
    };
    int*    tmp     = (int*)alloc((size_t)N * 4);
    int*    cursor  = (int*)alloc((size_t)N * 4);
    int*    offsets = (int*)alloc((size_t)(N + 1) * 4);
    int*    bsum    = (int*)alloc(4096 * 4);
    int*    bofs    = (int*)alloc(4096 * 4);
    // xfrag is dead after lin_mfma; csr (written by scatter_g, later) aliases it.
    size_t  xfrag_bytes = (size_t)nchunks * 16;
    size_t  csr_bytes   = (size_t)E * 16;
    char*   shared_reg  = (char*)alloc(xfrag_bytes > csr_bytes ? xfrag_bytes : csr_bytes);
    uint4*  xfrag   = (uint4*)shared_reg;
    i32x4*  csr     = (i32x4*)shared_reg;
    uint4*  wfrag   = (uint4*)alloc((size_t)8192 * 16);
    uint*   qbuf    = (uint*)alloc((size_t)N * 64 * 4);   // bf16 pairs
    uint*   sbuf    = (uint*)alloc((size_t)N * 64 * 4);   // bf16 pairs
    uint*   tbuf    = (uint*)alloc((size_t)N * 32 * 4);   // bf16 pairs [n][h*8+d/2]
    uint*   kvbuf   = (uint*)alloc((size_t)N * 128 * 4);  // bf16: k [0..63], v [64..127]
    (void)ws_size; (void)n_in; (void)out_size;

    hipMemsetAsync(tmp, 0, (size_t)N * 4, stream);
    hipMemsetAsync(cursor, 0, (size_t)N * 4, stream);

    pack_x<<<(nchunks + 255) / 256, 256, 0, stream>>>(x, xfrag, N, nchunks);
    pack_w<<<32, 256, 0, stream>>>(Wq, Wk, Wv, Wsk, wfrag);
    lin_mfma<<<NT, 256, 0, stream>>>(xfrag, wfrag, bq, bk, bv, bsk,
                                     qbuf, kvbuf, sbuf, N);
    t_kernel<<<(N + 3) / 4, 256, 0, stream>>>(qbuf, We, tbuf, N);
    hist_kernel<<<(E + 255) / 256, 256, 0, stream>>>(ei, tmp, E);
    int nb = (N + 1023) / 1024;
    scan1_kernel<<<nb, 1024, 0, stream>>>(tmp, bsum, N);
    scan2_kernel<<<1, 1024, 0, stream>>>(bsum, bofs, nb);
    scan3_kernel<<<nb, 1024, 0, stream>>>(tmp, bofs, offsets, N);
    scatter_g_kernel<<<(E + 255) / 256, 256, 0, stream>>>(ei, ei + E, ea, tbuf,
                                                          offsets, cursor, csr, E);
    agg_kernel<<<(N + 3) / 4, 256, 0, stream>>>(qbuf, kvbuf, sbuf, csr,
                                                offsets, Wbeta, out, N);
}

// Round 4
// 669.549 us; speedup vs baseline: 1.0414x; 1.0351x over previous
//
#include <hip/hip_runtime.h>
#include <stdint.h>

typedef unsigned int uint;
typedef unsigned short ushort;

typedef __attribute__((ext_vector_type(8))) short bf16x8;   // 8 bf16 = 4 VGPRs
typedef __attribute__((ext_vector_type(16))) float f32x16;  // MFMA 32x32 acc
typedef __attribute__((ext_vector_type(4))) int   i32x4;    // CSR record
typedef __attribute__((ext_vector_type(4))) float f32x4;

__device__ inline float bflo(uint u) {
    union { uint x; float f; } z; z.x = u << 16; return z.f;
}
__device__ inline float bfhi(uint u) {
    union { uint x; float f; } z; z.x = u & 0xffff0000u; return z.f;
}
__device__ inline ushort f2bf(float f) {
    union { float f; uint u; } x; x.f = f;
    uint r = (x.u + 0x7fffu + ((x.u >> 16) & 1u)) >> 16;
    return (ushort)r;
}

// ---------------------------------------------------------------------------
// pack_x: x (fp32 row-major) -> bf16 fragment-ordered tiles:
//   xfrag chunk index o = tile*2048 + kb*128 + m   (chunk = 16B = 8 bf16)
//   holds x[tile*128+m][kb*8 .. kb*8+8), zero-padded past n rows.
// ---------------------------------------------------------------------------
__global__ __launch_bounds__(256) void pack_x(const float* __restrict__ x,
                                              uint4* __restrict__ xfrag,
                                              int n, int nchunks)
{
    int o = blockIdx.x * 256 + threadIdx.x;
    if (o >= nchunks) return;
    int m    = o & 127;
    int kb   = (o >> 7) & 15;
    int tile = o >> 11;
    int row  = tile * 128 + m;
    float4 lo = make_float4(0.f, 0.f, 0.f, 0.f);
    float4 hi = make_float4(0.f, 0.f, 0.f, 0.f);
    if (row < n) {
        lo = *(const float4*)&x[(size_t)row * 128 + kb * 8];
        hi = *(const float4*)&x[(size_t)row * 128 + kb * 8 + 4];
    }
    uint4 ov;
    ov.x = (uint)f2bf(lo.x) | ((uint)f2bf(lo.y) << 16);
    ov.y = (uint)f2bf(lo.z) | ((uint)f2bf(lo.w) << 16);
    ov.z = (uint)f2bf(hi.x) | ((uint)f2bf(hi.y) << 16);
    ov.w = (uint)f2bf(hi.z) | ((uint)f2bf(hi.w) << 16);
    xfrag[o] = ov;
}

// ---------------------------------------------------------------------------
// pack_w: W_j (fp32 [K=128][N=128] row-major) -> bf16 B-fragment order.
// ---------------------------------------------------------------------------
__global__ __launch_bounds__(256) void pack_w(
    const float* __restrict__ W0, const float* __restrict__ W1,
    const float* __restrict__ W2, const float* __restrict__ W3,
    uint4* __restrict__ wfrag)
{
    int o = blockIdx.x * 256 + threadIdx.x;   // 4*16*128 = 8192 chunks
    if (o >= 8192) return;
    int nn = o & 127;
    int kb = (o >> 7) & 15;
    int j  = o >> 11;
    const float* W = (j == 0) ? W0 : (j == 1) ? W1 : (j == 2) ? W2 : W3;
    float v[8];
    #pragma unroll
    for (int i = 0; i < 8; ++i) v[i] = W[(size_t)(kb * 8 + i) * 128 + nn];
    uint4 ov;
    ov.x = (uint)f2bf(v[0]) | ((uint)f2bf(v[1]) << 16);
    ov.y = (uint)f2bf(v[2]) | ((uint)f2bf(v[3]) << 16);
    ov.z = (uint)f2bf(v[4]) | ((uint)f2bf(v[5]) << 16);
    ov.w = (uint)f2bf(v[6]) | ((uint)f2bf(v[7]) << 16);
    wfrag[o] = ov;
}

// ---------------------------------------------------------------------------
// lin_mfma: per block, 128 rows x all 4 weight matrices (512 cols), K=128.
// v_mfma_f32_32x32x16_bf16; C/D: col=lane&31, row=(reg&3)+8*(reg>>2)+4*(lane>>5).
// Outputs bf16-pair packed: q [n][64], kv [n][128] (k 0..63 | v 64..127),
// skip [n][64].
// ---------------------------------------------------------------------------
__global__ __launch_bounds__(256) void lin_mfma(
    const uint4* __restrict__ xfrag, const uint4* __restrict__ wfrag,
    const float* __restrict__ bq, const float* __restrict__ bk,
    const float* __restrict__ bv, const float* __restrict__ bs,
    uint* __restrict__ qout, uint* __restrict__ kvout, uint* __restrict__ sout,
    int n)
{
    const int tile = blockIdx.x;
    const int w  = threadIdx.x >> 6;
    const int l  = threadIdx.x & 63;
    const int lm = l & 31, lh = l >> 5;

    bf16x8 a[8];
    const uint4* ap = xfrag + (size_t)tile * 2048 + lh * 128 + w * 32 + lm;
    #pragma unroll
    for (int ks = 0; ks < 8; ++ks) a[ks] = *(const bf16x8*)(ap + ks * 256);

    const int rowbase = tile * 128 + w * 32 + 4 * lh;

    #pragma unroll
    for (int j = 0; j < 4; ++j) {
        const float* bias = (j == 0) ? bq : (j == 1) ? bk : (j == 2) ? bv : bs;
        uint* dst; int stride, cbase;
        if (j == 0)      { dst = qout;  stride = 64;  cbase = 0;  }
        else if (j == 1) { dst = kvout; stride = 128; cbase = 0;  }
        else if (j == 2) { dst = kvout; stride = 128; cbase = 64; }
        else             { dst = sout;  stride = 64;  cbase = 0;  }

        #pragma unroll
        for (int np = 0; np < 2; ++np) {       // ni pair {2np, 2np+1}
            const uint4* bp0 = wfrag + (size_t)j * 2048 + lh * 128 + (np * 2) * 32 + lm;
            f32x16 c0, c1;
            #pragma unroll
            for (int i = 0; i < 16; ++i) { c0[i] = 0.f; c1[i] = 0.f; }
            #pragma unroll
            for (int ks = 0; ks < 8; ++ks) {
                bf16x8 B0 = *(const bf16x8*)(bp0 + ks * 256);
                bf16x8 B1 = *(const bf16x8*)(bp0 + 32 + ks * 256);
                c0 = __builtin_amdgcn_mfma_f32_32x32x16_bf16(a[ks], B0, c0, 0, 0, 0);
                c1 = __builtin_amdgcn_mfma_f32_32x32x16_bf16(a[ks], B1, c1, 0, 0, 0);
            }
            #pragma unroll
            for (int t = 0; t < 2; ++t) {
                f32x16 cc = t ? c1 : c0;
                int gc = (np * 2 + t) * 32 + lm;
                float bl = bias[gc];
                #pragma unroll
                for (int r = 0; r < 16; ++r) {
                    float val = cc[r] + bl;
                    float partner = __shfl_xor(val, 1);
                    int gr = rowbase + (r & 3) + 8 * (r >> 2);
                    if (!(lm & 1) && gr < n) {
                        uint pk = (uint)f2bf(val) | ((uint)f2bf(partner) << 16);
                        dst[(size_t)gr * stride + cbase + (gc >> 1)] = pk;
                    }
                }
            }
        }
    }
}

// ---------------------------------------------------------------------------
// t[n,h,d] = sum_c We[d, h*32+c] * q[n, h*32+c]  — one wave per node,
// lane = h*16 + d. Output packed bf16 pairs: tb[n*32 + h*8 + d/2].
// ---------------------------------------------------------------------------
__global__ __launch_bounds__(256) void t_kernel(const uint* __restrict__ qb,
                                                const float* __restrict__ We,
                                                uint* __restrict__ tb, int n)
{
    int wid = (blockIdx.x * blockDim.x + threadIdx.x) >> 6;
    int lane = threadIdx.x & 63;
    if (wid >= n) return;
    int h = lane >> 4, d = lane & 15;
    const uint* qp = qb + (size_t)wid * 64 + h * 16;
    const float* wp = We + (size_t)d * 128 + h * 32;
    float s = 0.f;
    #pragma unroll
    for (int j4 = 0; j4 < 16; j4 += 4) {
        uint4 u = *(const uint4*)(qp + j4);
        float4 wA = *(const float4*)&wp[2 * j4];
        float4 wB = *(const float4*)&wp[2 * j4 + 4];
        s += bflo(u.x) * wA.x + bfhi(u.x) * wA.y
           + bflo(u.y) * wA.z + bfhi(u.y) * wA.w
           + bflo(u.z) * wB.x + bfhi(u.z) * wB.y
           + bflo(u.w) * wB.z + bfhi(u.w) * wB.w;
    }
    float partner = __shfl_xor(s, 1);
    if (!(lane & 1)) {
        uint pk = (uint)f2bf(s) | ((uint)f2bf(partner) << 16);
        tb[(size_t)wid * 32 + (lane >> 1)] = pk;
    }
}

// ---------------------------------------------------------------------------
// CSR build: histogram (returns per-edge rank) -> scan (3 kernels) ->
// fused scatter+g (atomic-free).
// ---------------------------------------------------------------------------
__global__ void hist_kernel(const int* __restrict__ rows, int* __restrict__ counts,
                            int* __restrict__ rank, int e)
{
    int i = blockIdx.x * blockDim.x + threadIdx.x;
    if (i < e) rank[i] = atomicAdd(&counts[rows[i]], 1);
}

__global__ __launch_bounds__(1024) void scan1_kernel(int* __restrict__ data,
                                                     int* __restrict__ bsum, int n)
{
    __shared__ int s[1024];
    int i = blockIdx.x * 1024 + threadIdx.x;
    int v = (i < n) ? data[i] : 0;
    s[threadIdx.x] = v;
    __syncthreads();
    for (int offd = 1; offd < 1024; offd <<= 1) {
        int add = (threadIdx.x >= offd) ? s[threadIdx.x - offd] : 0;
        __syncthreads();
        s[threadIdx.x] += add;
        __syncthreads();
    }
    if (i < n) data[i] = s[threadIdx.x];
    if (threadIdx.x == 1023) bsum[blockIdx.x] = s[1023];
}

__global__ __launch_bounds__(1024) void scan2_kernel(const int* __restrict__ bsum,
                                                     int* __restrict__ bofs, int nb)
{
    __shared__ int s[1024];
    int tid = threadIdx.x;
    int v = (tid < nb) ? bsum[tid] : 0;
    s[tid] = v;
    __syncthreads();
    for (int o = 1; o < 1024; o <<= 1) {
        int add = (tid >= o) ? s[tid - o] : 0;
        __syncthreads();
        s[tid] += add;
        __syncthreads();
    }
    if (tid < nb) bofs[tid] = s[tid] - v;
}

__global__ __launch_bounds__(1024) void scan3_kernel(const int* __restrict__ incl,
                                                     const int* __restrict__ bofs,
                                                     int* __restrict__ offsets, int n)
{
    int i = blockIdx.x * 1024 + threadIdx.x;
    if (i == 0) offsets[0] = 0;
    if (i < n) offsets[i + 1] = incl[i] + bofs[blockIdx.x];
}

// ---------------------------------------------------------------------------
// Fused scatter + edge-logit precompute, ATOMIC-FREE: pos comes from the
// rank captured by hist's atomic. Dependency chain for the record store is
// just {rows[i], rank[i]} -> offsets[r] -> store; it overlaps the ea stream.
//   g[h] = sum_d ea[e,d] * t[row_e, h, d]       (the q·(ea@We) logit term)
// CSR record (16B): {src, 0, bf16pack(g0,g1), bf16pack(g2,g3)}.
// ea is read-once -> non-temporal (via ext-vector f32x4 — HIP float4 is a
// class type and rejected by the builtin), keeps tb resident in L2.
// ---------------------------------------------------------------------------
__global__ __launch_bounds__(256) void scatter_g_kernel(
    const int* __restrict__ rows, const int* __restrict__ cols,
    const float* __restrict__ ea, const uint* __restrict__ tb,
    const int* __restrict__ offsets, const int* __restrict__ rank,
    i32x4* __restrict__ csr, int e)
{
    int i = blockIdx.x * blockDim.x + threadIdx.x;
    if (i >= e) return;
    int r  = rows[i];
    int rk = rank[i];
    int c  = cols[i];
    int pos = offsets[r] + rk;

    const f32x4* ep = (const f32x4*)&ea[(size_t)i * 16];
    f32x4 e0 = __builtin_nontemporal_load(ep);
    f32x4 e1 = __builtin_nontemporal_load(ep + 1);
    f32x4 e2 = __builtin_nontemporal_load(ep + 2);
    f32x4 e3 = __builtin_nontemporal_load(ep + 3);
    const uint* tp = tb + (size_t)r * 32;
    float g[4];
    #pragma unroll
    for (int h = 0; h < 4; ++h) {
        uint4 ua = *(const uint4*)(tp + h * 8);
        uint4 ub = *(const uint4*)(tp + h * 8 + 4);
        g[h] = e0[0] * bflo(ua.x) + e0[1] * bfhi(ua.x)
             + e0[2] * bflo(ua.y) + e0[3] * bfhi(ua.y)
             + e1[0] * bflo(ua.z) + e1[1] * bfhi(ua.z)
             + e1[2] * bflo(ua.w) + e1[3] * bfhi(ua.w)
             + e2[0] * bflo(ub.x) + e2[1] * bfhi(ub.x)
             + e2[2] * bflo(ub.y) + e2[3] * bfhi(ub.y)
             + e3[0] * bflo(ub.z) + e3[1] * bfhi(ub.z)
             + e3[2] * bflo(ub.w) + e3[3] * bfhi(ub.w);
    }
    i32x4 rec;
    rec.x = c;
    rec.y = 0;
    rec.z = (int)((uint)f2bf(g[0]) | ((uint)f2bf(g[1]) << 16));
    rec.w = (int)((uint)f2bf(g[2]) | ((uint)f2bf(g[3]) << 16));
    csr[pos] = rec;
}

// ---------------------------------------------------------------------------
// Aggregation: one wave per destination node, 4 edges in parallel.
// lane = es*16 + h*4 + cq. Lane owns channels c0 = h*32+cq*8 .. +8 of its
// edge slot. The ea@We logit term arrives as bf16 g in the CSR record.
// csr is read-once -> non-temporal, keeps kv (gathered) resident in L2.
// ---------------------------------------------------------------------------
__global__ __launch_bounds__(256) void agg_kernel(
    const uint* __restrict__ qb, const uint* __restrict__ kv,
    const uint* __restrict__ sb, const i32x4* __restrict__ csr,
    const int* __restrict__ offsets, const float* __restrict__ Wbeta,
    float* __restrict__ out, int n)
{
    int wid = (blockIdx.x * blockDim.x + threadIdx.x) >> 6;
    int lane = threadIdx.x & 63;
    if (wid >= n) return;
    const int es = lane >> 4;
    const int h  = (lane >> 2) & 3;
    const int cq = lane & 3;
    const int c0 = h * 32 + cq * 8;

    uint4 uq = *(const uint4*)&qb[(size_t)wid * 64 + h * 16 + cq * 4];
    float qv[8] = { bflo(uq.x), bfhi(uq.x), bflo(uq.y), bfhi(uq.y),
                    bflo(uq.z), bfhi(uq.z), bflo(uq.w), bfhi(uq.w) };

    const int beg = offsets[wid], end = offsets[wid + 1];
    const float scale = 0.17677669529663687f;  // 1/sqrt(32)

    float denom = 0.f;
    float acc[8];
    #pragma unroll
    for (int j = 0; j < 8; ++j) acc[j] = 0.f;

    for (int i = beg; i < end; i += 4) {
        int idx = i + es;
        bool valid = idx < end;
        int cidx = valid ? idx : end - 1;
        i32x4 se = __builtin_nontemporal_load(&csr[cidx]);
        uint gp = (h & 2) ? (uint)se.w : (uint)se.z;
        float gh = (h & 1) ? bfhi(gp) : bflo(gp);
        const uint* krow = kv + (size_t)se.x * 128 + h * 16 + cq * 4;
        uint4 kp = *(const uint4*)krow;
        uint4 vp = *(const uint4*)(krow + 64);

        float part = qv[0] * bflo(kp.x) + qv[1] * bfhi(kp.x)
                   + qv[2] * bflo(kp.y) + qv[3] * bfhi(kp.y)
                   + qv[4] * bflo(kp.z) + qv[5] * bfhi(kp.z)
                   + qv[6] * bflo(kp.w) + qv[7] * bfhi(kp.w);
        part += __shfl_xor(part, 1);
        part += __shfl_xor(part, 2);
        float p = valid ? __expf((part + gh) * scale) : 0.f;
        denom += p;
        acc[0] += p * bflo(vp.x); acc[1] += p * bfhi(vp.x);
        acc[2] += p * bflo(vp.y); acc[3] += p * bfhi(vp.y);
        acc[4] += p * bflo(vp.z); acc[5] += p * bfhi(vp.z);
        acc[6] += p * bflo(vp.w); acc[7] += p * bfhi(vp.w);
    }

    denom += __shfl_xor(denom, 16);
    denom += __shfl_xor(denom, 32);
    #pragma unroll
    for (int j = 0; j < 8; ++j) {
        acc[j] += __shfl_xor(acc[j], 16);
        acc[j] += __shfl_xor(acc[j], 32);
    }

    float inv = 1.f / (denom + 1e-16f);
    float o[8];
    #pragma unroll
    for (int j = 0; j < 8; ++j) o[j] = acc[j] * inv;

    uint4 us = *(const uint4*)&sb[(size_t)wid * 64 + h * 16 + cq * 4];
    float xsv[8] = { bflo(us.x), bfhi(us.x), bflo(us.y), bfhi(us.y),
                     bflo(us.z), bfhi(us.z), bflo(us.w), bfhi(us.w) };

    float bp = 0.f;
    #pragma unroll
    for (int j = 0; j < 8; ++j) {
        bp += o[j]   * Wbeta[c0 + j]
            + xsv[j] * Wbeta[128 + c0 + j]
            + (o[j] - xsv[j]) * Wbeta[256 + c0 + j];
    }
    bp += __shfl_xor(bp, 1);
    bp += __shfl_xor(bp, 2);
    bp += __shfl_xor(bp, 4);
    bp += __shfl_xor(bp, 8);
    float beta = 1.f / (1.f + __expf(-bp));

    if (es == 0) {
        float r[8];
        #pragma unroll
        for (int j = 0; j < 8; ++j) r[j] = beta * xsv[j] + (1.f - beta) * o[j];
        f32x4 r0 = { r[0], r[1], r[2], r[3] };
        f32x4 r1 = { r[4], r[5], r[6], r[7] };
        __builtin_nontemporal_store(r0, (f32x4*)&out[(size_t)wid * 128 + c0]);
        __builtin_nontemporal_store(r1, (f32x4*)&out[(size_t)wid * 128 + c0 + 4]);
    }
}

// ---------------------------------------------------------------------------
extern "C" void kernel_launch(void* const* d_in, const int* in_sizes, int n_in,
                              void* d_out, int out_size, void* d_ws, size_t ws_size,
                              hipStream_t stream)
{
    const float* x     = (const float*)d_in[0];
    const float* ea    = (const float*)d_in[1];
    const int*   ei    = (const int*)d_in[2];   // [0:E)=row(dst), [E:2E)=col(src)
    const float* Wq    = (const float*)d_in[3];
    const float* bq    = (const float*)d_in[4];
    const float* Wk    = (const float*)d_in[5];
    const float* bk    = (const float*)d_in[6];
    const float* Wv    = (const float*)d_in[7];
    const float* bv    = (const float*)d_in[8];
    const float* We    = (const float*)d_in[9];
    const float* Wsk   = (const float*)d_in[10];
    const float* bsk   = (const float*)d_in[11];
    const float* Wbeta = (const float*)d_in[12];
    float* out = (float*)d_out;

    const int N = in_sizes[0] / 128;
    const int E = in_sizes[1] / 16;
    const int NT = (N + 127) / 128;         // 128-row tiles
    const int nchunks = NT * 2048;

    char* base = (char*)d_ws;
    size_t off = 0;
    auto alloc = [&](size_t bytes) -> void* {
        void* p = base + off;
        off += (bytes + 255) & ~(size_t)255;
        return p;
    };
    int*    tmp     = (int*)alloc((size_t)N * 4);
    int*    offsets = (int*)alloc((size_t)(N + 1) * 4);
    int*    bsum    = (int*)alloc(4096 * 4);
    int*    bofs    = (int*)alloc(4096 * 4);
    int*    rank    = (int*)alloc((size_t)E * 4);
    // xfrag is dead after lin_mfma; csr (written by scatter_g, later) aliases it.
    size_t  xfrag_bytes = (size_t)nchunks * 16;
    size_t  csr_bytes   = (size_t)E * 16;
    char*   shared_reg  = (char*)alloc(xfrag_bytes > csr_bytes ? xfrag_bytes : csr_bytes);
    uint4*  xfrag   = (uint4*)shared_reg;
    i32x4*  csr     = (i32x4*)shared_reg;
    uint4*  wfrag   = (uint4*)alloc((size_t)8192 * 16);
    uint*   qbuf    = (uint*)alloc((size_t)N * 64 * 4);   // bf16 pairs
    uint*   sbuf    = (uint*)alloc((size_t)N * 64 * 4);   // bf16 pairs
    uint*   tbuf    = (uint*)alloc((size_t)N * 32 * 4);   // bf16 pairs [n][h*8+d/2]
    uint*   kvbuf   = (uint*)alloc((size_t)N * 128 * 4);  // bf16: k [0..63], v [64..127]
    (void)ws_size; (void)n_in; (void)out_size;

    hipMemsetAsync(tmp, 0, (size_t)N * 4, stream);

    pack_x<<<(nchunks + 255) / 256, 256, 0, stream>>>(x, xfrag, N, nchunks);
    pack_w<<<32, 256, 0, stream>>>(Wq, Wk, Wv, Wsk, wfrag);
    lin_mfma<<<NT, 256, 0, stream>>>(xfrag, wfrag, bq, bk, bv, bsk,
                                     qbuf, kvbuf, sbuf, N);
    t_kernel<<<(N + 3) / 4, 256, 0, stream>>>(qbuf, We, tbuf, N);
    hist_kernel<<<(E + 255) / 256, 256, 0, stream>>>(ei, tmp, rank, E);
    int nb = (N + 1023) / 1024;
    scan1_kernel<<<nb, 1024, 0, stream>>>(tmp, bsum, N);
    scan2_kernel<<<1, 1024, 0, stream>>>(bsum, bofs, nb);
    scan3_kernel<<<nb, 1024, 0, stream>>>(tmp, bofs, offsets, N);
    scatter_g_kernel<<<(E + 255) / 256, 256, 0, stream>>>(ei, ei + E, ea, tbuf,
                                                          offsets, rank, csr, E);
    agg_kernel<<<(N + 3) / 4, 256, 0, stream>>>(qbuf, kvbuf, sbuf, csr,
                                                offsets, Wbeta, out, N);
}

// Round 5
// 594.224 us; speedup vs baseline: 1.1735x; 1.1268x over previous
//
#include <hip/hip_runtime.h>
#include <stdint.h>

typedef unsigned int uint;
typedef unsigned short ushort;

typedef __attribute__((ext_vector_type(8))) short bf16x8;   // 8 bf16 = 4 VGPRs
typedef __attribute__((ext_vector_type(16))) float f32x16;  // MFMA 32x32 acc
typedef __attribute__((ext_vector_type(4))) int   i32x4;    // CSR record
typedef __attribute__((ext_vector_type(4))) float f32x4;

__device__ inline float bflo(uint u) {
    union { uint x; float f; } z; z.x = u << 16; return z.f;
}
__device__ inline float bfhi(uint u) {
    union { uint x; float f; } z; z.x = u & 0xffff0000u; return z.f;
}
__device__ inline ushort f2bf(float f) {
    union { float f; uint u; } x; x.f = f;
    uint r = (x.u + 0x7fffu + ((x.u >> 16) & 1u)) >> 16;
    return (ushort)r;
}

// ---------------------------------------------------------------------------
// pack_x: x (fp32 row-major) -> bf16 fragment-ordered tiles:
//   xfrag chunk index o = tile*2048 + kb*128 + m   (chunk = 16B = 8 bf16)
//   holds x[tile*128+m][kb*8 .. kb*8+8), zero-padded past n rows.
// ---------------------------------------------------------------------------
__global__ __launch_bounds__(256) void pack_x(const float* __restrict__ x,
                                              uint4* __restrict__ xfrag,
                                              int n, int nchunks)
{
    int o = blockIdx.x * 256 + threadIdx.x;
    if (o >= nchunks) return;
    int m    = o & 127;
    int kb   = (o >> 7) & 15;
    int tile = o >> 11;
    int row  = tile * 128 + m;
    float4 lo = make_float4(0.f, 0.f, 0.f, 0.f);
    float4 hi = make_float4(0.f, 0.f, 0.f, 0.f);
    if (row < n) {
        lo = *(const float4*)&x[(size_t)row * 128 + kb * 8];
        hi = *(const float4*)&x[(size_t)row * 128 + kb * 8 + 4];
    }
    uint4 ov;
    ov.x = (uint)f2bf(lo.x) | ((uint)f2bf(lo.y) << 16);
    ov.y = (uint)f2bf(lo.z) | ((uint)f2bf(lo.w) << 16);
    ov.z = (uint)f2bf(hi.x) | ((uint)f2bf(hi.y) << 16);
    ov.w = (uint)f2bf(hi.z) | ((uint)f2bf(hi.w) << 16);
    xfrag[o] = ov;
}

// ---------------------------------------------------------------------------
// pack_w: W_j (fp32 [K=128][N=128] row-major) -> bf16 B-fragment order for
// j=0..3 (Wq,Wk,Wv,Wskip).  Section j=4 (chunks 8192..10239) computes the
// FOLDED t-projection Wt[k, h*16+d] = sum_c Wq[k,h*32+c]*We[d,h*32+c]
// (cols 64..127 zero) and bt = bq @ (same), so t = x@Wt + bt can ride the
// main MFMA kernel and t_kernel disappears.
// ---------------------------------------------------------------------------
__global__ __launch_bounds__(256) void pack_w(
    const float* __restrict__ W0, const float* __restrict__ W1,
    const float* __restrict__ W2, const float* __restrict__ W3,
    const float* __restrict__ We, const float* __restrict__ bq,
    uint4* __restrict__ wfrag, float* __restrict__ btbuf)
{
    int o = blockIdx.x * 256 + threadIdx.x;   // 5*16*128 = 10240 chunks
    if (o >= 10240) return;
    float v[8];
    if (o < 8192) {
        int nn = o & 127;
        int kb = (o >> 7) & 15;
        int j  = o >> 11;
        const float* W = (j == 0) ? W0 : (j == 1) ? W1 : (j == 2) ? W2 : W3;
        #pragma unroll
        for (int i = 0; i < 8; ++i) v[i] = W[(size_t)(kb * 8 + i) * 128 + nn];
    } else {
        int o2 = o - 8192;
        int nn = o2 & 127;
        int kb = (o2 >> 7) & 15;
        #pragma unroll
        for (int i = 0; i < 8; ++i) v[i] = 0.f;
        if (nn < 64) {
            int h = nn >> 4, d = nn & 15;
            const float* wq = W0 + h * 32;          // Wq[k][h*32 + c]
            const float* we = We + (size_t)d * 128 + h * 32;
            #pragma unroll
            for (int i = 0; i < 8; ++i) {
                int k = kb * 8 + i;
                float s = 0.f;
                for (int c = 0; c < 32; ++c)
                    s += wq[(size_t)k * 128 + c] * we[c];
                v[i] = s;
            }
            if (kb == 0) {
                float s = 0.f;
                for (int c = 0; c < 32; ++c) s += bq[h * 32 + c] * we[c];
                btbuf[nn] = s;
            }
        }
    }
    uint4 ov;
    ov.x = (uint)f2bf(v[0]) | ((uint)f2bf(v[1]) << 16);
    ov.y = (uint)f2bf(v[2]) | ((uint)f2bf(v[3]) << 16);
    ov.z = (uint)f2bf(v[4]) | ((uint)f2bf(v[5]) << 16);
    ov.w = (uint)f2bf(v[6]) | ((uint)f2bf(v[7]) << 16);
    wfrag[o] = ov;
}

// ---------------------------------------------------------------------------
// lin_mfma: per block, 128 rows x 5 weight matrices (576 cols), K=128.
// v_mfma_f32_32x32x16_bf16; C/D: col=lane&31, row=(reg&3)+8*(reg>>2)+4*(lane>>5).
// Outputs bf16-pair packed: q [n][64], kv [n][128] (k 0..63 | v 64..127),
// skip [n][64], t [n][32]  (t = x@Wt+bt, 64 cols).
// ---------------------------------------------------------------------------
__global__ __launch_bounds__(256) void lin_mfma(
    const uint4* __restrict__ xfrag, const uint4* __restrict__ wfrag,
    const float* __restrict__ bq, const float* __restrict__ bk,
    const float* __restrict__ bv, const float* __restrict__ bs,
    const float* __restrict__ bt,
    uint* __restrict__ qout, uint* __restrict__ kvout, uint* __restrict__ sout,
    uint* __restrict__ tout, int n)
{
    const int tile = blockIdx.x;
    const int w  = threadIdx.x >> 6;
    const int l  = threadIdx.x & 63;
    const int lm = l & 31, lh = l >> 5;

    bf16x8 a[8];
    const uint4* ap = xfrag + (size_t)tile * 2048 + lh * 128 + w * 32 + lm;
    #pragma unroll
    for (int ks = 0; ks < 8; ++ks) a[ks] = *(const bf16x8*)(ap + ks * 256);

    const int rowbase = tile * 128 + w * 32 + 4 * lh;

    #pragma unroll
    for (int j = 0; j < 5; ++j) {
        const float* bias = (j == 0) ? bq : (j == 1) ? bk : (j == 2) ? bv
                          : (j == 3) ? bs : bt;
        uint* dst; int stride, cbase;
        if (j == 0)      { dst = qout;  stride = 64;  cbase = 0;  }
        else if (j == 1) { dst = kvout; stride = 128; cbase = 0;  }
        else if (j == 2) { dst = kvout; stride = 128; cbase = 64; }
        else if (j == 3) { dst = sout;  stride = 64;  cbase = 0;  }
        else             { dst = tout;  stride = 32;  cbase = 0;  }
        const int npc = (j == 4) ? 1 : 2;

        #pragma unroll
        for (int np = 0; np < npc; ++np) {       // ni pair {2np, 2np+1}
            const uint4* bp0 = wfrag + (size_t)j * 2048 + lh * 128 + (np * 2) * 32 + lm;
            f32x16 c0, c1;
            #pragma unroll
            for (int i = 0; i < 16; ++i) { c0[i] = 0.f; c1[i] = 0.f; }
            #pragma unroll
            for (int ks = 0; ks < 8; ++ks) {
                bf16x8 B0 = *(const bf16x8*)(bp0 + ks * 256);
                bf16x8 B1 = *(const bf16x8*)(bp0 + 32 + ks * 256);
                c0 = __builtin_amdgcn_mfma_f32_32x32x16_bf16(a[ks], B0, c0, 0, 0, 0);
                c1 = __builtin_amdgcn_mfma_f32_32x32x16_bf16(a[ks], B1, c1, 0, 0, 0);
            }
            #pragma unroll
            for (int t = 0; t < 2; ++t) {
                f32x16 cc = t ? c1 : c0;
                int gc = (np * 2 + t) * 32 + lm;
                float bl = bias[gc];
                #pragma unroll
                for (int r = 0; r < 16; ++r) {
                    float val = cc[r] + bl;
                    float partner = __shfl_xor(val, 1);
                    int gr = rowbase + (r & 3) + 8 * (r >> 2);
                    if (!(lm & 1) && gr < n) {
                        uint pk = (uint)f2bf(val) | ((uint)f2bf(partner) << 16);
                        dst[(size_t)gr * stride + cbase + (gc >> 1)] = pk;
                    }
                }
            }
        }
    }
}

// ---------------------------------------------------------------------------
// CSR build: histogram (returns per-edge rank) -> scan (2 kernels) ->
// fused scatter+g (atomic-free).
// ---------------------------------------------------------------------------
__global__ void hist_kernel(const int* __restrict__ rows, int* __restrict__ counts,
                            int* __restrict__ rank, int e)
{
    int i = blockIdx.x * blockDim.x + threadIdx.x;
    if (i < e) rank[i] = atomicAdd(&counts[rows[i]], 1);
}

__global__ __launch_bounds__(1024) void scan1_kernel(int* __restrict__ data,
                                                     int* __restrict__ bsum, int n)
{
    __shared__ int s[1024];
    int i = blockIdx.x * 1024 + threadIdx.x;
    int v = (i < n) ? data[i] : 0;
    s[threadIdx.x] = v;
    __syncthreads();
    for (int offd = 1; offd < 1024; offd <<= 1) {
        int add = (threadIdx.x >= offd) ? s[threadIdx.x - offd] : 0;
        __syncthreads();
        s[threadIdx.x] += add;
        __syncthreads();
    }
    if (i < n) data[i] = s[threadIdx.x];
    if (threadIdx.x == 1023) bsum[blockIdx.x] = s[1023];
}

// fused scan2+scan3: every block redoes the (cheap) 1024-wide scan of bsum
// in LDS and picks its own exclusive prefix; then emits offsets.
__global__ __launch_bounds__(1024) void scan23_kernel(const int* __restrict__ incl,
                                                      const int* __restrict__ bsum,
                                                      int* __restrict__ offsets,
                                                      int n, int nb)
{
    __shared__ int s[1024];
    int tid = threadIdx.x;
    int v = (tid < nb) ? bsum[tid] : 0;
    s[tid] = v;
    __syncthreads();
    for (int o = 1; o < 1024; o <<= 1) {
        int add = (tid >= o) ? s[tid - o] : 0;
        __syncthreads();
        s[tid] += add;
        __syncthreads();
    }
    int bofs = (blockIdx.x == 0) ? 0 : s[blockIdx.x - 1];
    int i = blockIdx.x * 1024 + tid;
    if (i == 0) offsets[0] = 0;
    if (i < n) offsets[i + 1] = incl[i] + bofs;
}

// ---------------------------------------------------------------------------
// Fused scatter + edge-logit precompute, ATOMIC-FREE: pos comes from the
// rank captured by hist's atomic.
//   g[h] = sum_d ea[e,d] * t[row_e, h, d]       (the q·(ea@We) logit term)
// CSR record (16B): {src, 0, bf16pack(g0,g1), bf16pack(g2,g3)}.
// ea read-once -> NT load; csr record store NT (scattered 16B stores would
// otherwise RFO + rewrite lines ~4x: WRITE_SIZE was 100MB vs 25.6 ideal) and
// would evict the tb gather target from L2.
// ---------------------------------------------------------------------------
__global__ __launch_bounds__(256) void scatter_g_kernel(
    const int* __restrict__ rows, const int* __restrict__ cols,
    const float* __restrict__ ea, const uint* __restrict__ tb,
    const int* __restrict__ offsets, const int* __restrict__ rank,
    i32x4* __restrict__ csr, int e)
{
    int i = blockIdx.x * blockDim.x + threadIdx.x;
    if (i >= e) return;
    int r  = rows[i];
    int rk = rank[i];
    int c  = cols[i];
    int pos = offsets[r] + rk;

    const f32x4* ep = (const f32x4*)&ea[(size_t)i * 16];
    f32x4 e0 = __builtin_nontemporal_load(ep);
    f32x4 e1 = __builtin_nontemporal_load(ep + 1);
    f32x4 e2 = __builtin_nontemporal_load(ep + 2);
    f32x4 e3 = __builtin_nontemporal_load(ep + 3);
    const uint* tp = tb + (size_t)r * 32;
    float g[4];
    #pragma unroll
    for (int h = 0; h < 4; ++h) {
        uint4 ua = *(const uint4*)(tp + h * 8);
        uint4 ub = *(const uint4*)(tp + h * 8 + 4);
        g[h] = e0[0] * bflo(ua.x) + e0[1] * bfhi(ua.x)
             + e0[2] * bflo(ua.y) + e0[3] * bfhi(ua.y)
             + e1[0] * bflo(ua.z) + e1[1] * bfhi(ua.z)
             + e1[2] * bflo(ua.w) + e1[3] * bfhi(ua.w)
             + e2[0] * bflo(ub.x) + e2[1] * bfhi(ub.x)
             + e2[2] * bflo(ub.y) + e2[3] * bfhi(ub.y)
             + e3[0] * bflo(ub.z) + e3[1] * bfhi(ub.z)
             + e3[2] * bflo(ub.w) + e3[3] * bfhi(ub.w);
    }
    i32x4 rec;
    rec.x = c;
    rec.y = 0;
    rec.z = (int)((uint)f2bf(g[0]) | ((uint)f2bf(g[1]) << 16));
    rec.w = (int)((uint)f2bf(g[2]) | ((uint)f2bf(g[3]) << 16));
    __builtin_nontemporal_store(rec, &csr[pos]);
}

// ---------------------------------------------------------------------------
// Aggregation: one wave per destination node, 4 edges in parallel.
// lane = es*16 + h*4 + cq. Lane owns channels c0 = h*32+cq*8 .. +8 of its
// edge slot. The ea@We logit term arrives as bf16 g in the CSR record.
// csr is read-once -> non-temporal, keeps kv (gathered) resident in L2.
// ---------------------------------------------------------------------------
__global__ __launch_bounds__(256) void agg_kernel(
    const uint* __restrict__ qb, const uint* __restrict__ kv,
    const uint* __restrict__ sb, const i32x4* __restrict__ csr,
    const int* __restrict__ offsets, const float* __restrict__ Wbeta,
    float* __restrict__ out, int n)
{
    int wid = (blockIdx.x * blockDim.x + threadIdx.x) >> 6;
    int lane = threadIdx.x & 63;
    if (wid >= n) return;
    const int es = lane >> 4;
    const int h  = (lane >> 2) & 3;
    const int cq = lane & 3;
    const int c0 = h * 32 + cq * 8;

    uint4 uq = *(const uint4*)&qb[(size_t)wid * 64 + h * 16 + cq * 4];
    float qv[8] = { bflo(uq.x), bfhi(uq.x), bflo(uq.y), bfhi(uq.y),
                    bflo(uq.z), bfhi(uq.z), bflo(uq.w), bfhi(uq.w) };

    const int beg = offsets[wid], end = offsets[wid + 1];
    const float scale = 0.17677669529663687f;  // 1/sqrt(32)

    float denom = 0.f;
    float acc[8];
    #pragma unroll
    for (int j = 0; j < 8; ++j) acc[j] = 0.f;

    for (int i = beg; i < end; i += 4) {
        int idx = i + es;
        bool valid = idx < end;
        int cidx = valid ? idx : end - 1;
        i32x4 se = __builtin_nontemporal_load(&csr[cidx]);
        uint gp = (h & 2) ? (uint)se.w : (uint)se.z;
        float gh = (h & 1) ? bfhi(gp) : bflo(gp);
        const uint* krow = kv + (size_t)se.x * 128 + h * 16 + cq * 4;
        uint4 kp = *(const uint4*)krow;
        uint4 vp = *(const uint4*)(krow + 64);

        float part = qv[0] * bflo(kp.x) + qv[1] * bfhi(kp.x)
                   + qv[2] * bflo(kp.y) + qv[3] * bfhi(kp.y)
                   + qv[4] * bflo(kp.z) + qv[5] * bfhi(kp.z)
                   + qv[6] * bflo(kp.w) + qv[7] * bfhi(kp.w);
        part += __shfl_xor(part, 1);
        part += __shfl_xor(part, 2);
        float p = valid ? __expf((part + gh) * scale) : 0.f;
        denom += p;
        acc[0] += p * bflo(vp.x); acc[1] += p * bfhi(vp.x);
        acc[2] += p * bflo(vp.y); acc[3] += p * bfhi(vp.y);
        acc[4] += p * bflo(vp.z); acc[5] += p * bfhi(vp.z);
        acc[6] += p * bflo(vp.w); acc[7] += p * bfhi(vp.w);
    }

    denom += __shfl_xor(denom, 16);
    denom += __shfl_xor(denom, 32);
    #pragma unroll
    for (int j = 0; j < 8; ++j) {
        acc[j] += __shfl_xor(acc[j], 16);
        acc[j] += __shfl_xor(acc[j], 32);
    }

    float inv = 1.f / (denom + 1e-16f);
    float o[8];
    #pragma unroll
    for (int j = 0; j < 8; ++j) o[j] = acc[j] * inv;

    uint4 us = *(const uint4*)&sb[(size_t)wid * 64 + h * 16 + cq * 4];
    float xsv[8] = { bflo(us.x), bfhi(us.x), bflo(us.y), bfhi(us.y),
                     bflo(us.z), bfhi(us.z), bflo(us.w), bfhi(us.w) };

    float bp = 0.f;
    #pragma unroll
    for (int j = 0; j < 8; ++j) {
        bp += o[j]   * Wbeta[c0 + j]
            + xsv[j] * Wbeta[128 + c0 + j]
            + (o[j] - xsv[j]) * Wbeta[256 + c0 + j];
    }
    bp += __shfl_xor(bp, 1);
    bp += __shfl_xor(bp, 2);
    bp += __shfl_xor(bp, 4);
    bp += __shfl_xor(bp, 8);
    float beta = 1.f / (1.f + __expf(-bp));

    if (es == 0) {
        float r[8];
        #pragma unroll
        for (int j = 0; j < 8; ++j) r[j] = beta * xsv[j] + (1.f - beta) * o[j];
        f32x4 r0 = { r[0], r[1], r[2], r[3] };
        f32x4 r1 = { r[4], r[5], r[6], r[7] };
        __builtin_nontemporal_store(r0, (f32x4*)&out[(size_t)wid * 128 + c0]);
        __builtin_nontemporal_store(r1, (f32x4*)&out[(size_t)wid * 128 + c0 + 4]);
    }
}

// ---------------------------------------------------------------------------
extern "C" void kernel_launch(void* const* d_in, const int* in_sizes, int n_in,
                              void* d_out, int out_size, void* d_ws, size_t ws_size,
                              hipStream_t stream)
{
    const float* x     = (const float*)d_in[0];
    const float* ea    = (const float*)d_in[1];
    const int*   ei    = (const int*)d_in[2];   // [0:E)=row(dst), [E:2E)=col(src)
    const float* Wq    = (const float*)d_in[3];
    const float* bq    = (const float*)d_in[4];
    const float* Wk    = (const float*)d_in[5];
    const float* bk    = (const float*)d_in[6];
    const float* Wv    = (const float*)d_in[7];
    const float* bv    = (const float*)d_in[8];
    const float* We    = (const float*)d_in[9];
    const float* Wsk   = (const float*)d_in[10];
    const float* bsk   = (const float*)d_in[11];
    const float* Wbeta = (const float*)d_in[12];
    float* out = (float*)d_out;

    const int N = in_sizes[0] / 128;
    const int E = in_sizes[1] / 16;
    const int NT = (N + 127) / 128;         // 128-row tiles
    const int nchunks = NT * 2048;

    char* base = (char*)d_ws;
    size_t off = 0;
    auto alloc = [&](size_t bytes) -> void* {
        void* p = base + off;
        off += (bytes + 255) & ~(size_t)255;
        return p;
    };
    int*    tmp     = (int*)alloc((size_t)N * 4);
    int*    offsets = (int*)alloc((size_t)(N + 1) * 4);
    int*    bsum    = (int*)alloc(4096 * 4);
    int*    rank    = (int*)alloc((size_t)E * 4);
    float*  btbuf   = (float*)alloc(256);
    // xfrag is dead after lin_mfma; csr (written by scatter_g, later) aliases it.
    size_t  xfrag_bytes = (size_t)nchunks * 16;
    size_t  csr_bytes   = (size_t)E * 16;
    char*   shared_reg  = (char*)alloc(xfrag_bytes > csr_bytes ? xfrag_bytes : csr_bytes);
    uint4*  xfrag   = (uint4*)shared_reg;
    i32x4*  csr     = (i32x4*)shared_reg;
    uint4*  wfrag   = (uint4*)alloc((size_t)10240 * 16);  // 5 matrices
    uint*   qbuf    = (uint*)alloc((size_t)N * 64 * 4);   // bf16 pairs
    uint*   sbuf    = (uint*)alloc((size_t)N * 64 * 4);   // bf16 pairs
    uint*   tbuf    = (uint*)alloc((size_t)N * 32 * 4);   // bf16 pairs [n][h*8+d/2]
    uint*   kvbuf   = (uint*)alloc((size_t)N * 128 * 4);  // bf16: k [0..63], v [64..127]
    (void)ws_size; (void)n_in; (void)out_size;

    hipMemsetAsync(tmp, 0, (size_t)N * 4, stream);

    pack_x<<<(nchunks + 255) / 256, 256, 0, stream>>>(x, xfrag, N, nchunks);
    pack_w<<<40, 256, 0, stream>>>(Wq, Wk, Wv, Wsk, We, bq, wfrag, btbuf);
    lin_mfma<<<NT, 256, 0, stream>>>(xfrag, wfrag, bq, bk, bv, bsk, btbuf,
                                     qbuf, kvbuf, sbuf, tbuf, N);
    hist_kernel<<<(E + 255) / 256, 256, 0, stream>>>(ei, tmp, rank, E);
    int nb = (N + 1023) / 1024;
    scan1_kernel<<<nb, 1024, 0, stream>>>(tmp, bsum, N);
    scan23_kernel<<<nb, 1024, 0, stream>>>(tmp, bsum, offsets, N, nb);
    scatter_g_kernel<<<(E + 255) / 256, 256, 0, stream>>>(ei, ei + E, ea, tbuf,
                                                          offsets, rank, csr, E);
    agg_kernel<<<(N + 3) / 4, 256, 0, stream>>>(qbuf, kvbuf, sbuf, csr,
                                                offsets, Wbeta, out, N);
}

// Round 6
// 583.819 us; speedup vs baseline: 1.1944x; 1.0178x over previous
//
#include <hip/hip_runtime.h>
#include <stdint.h>

typedef unsigned int uint;
typedef unsigned short ushort;

typedef __attribute__((ext_vector_type(8))) short bf16x8;   // 8 bf16 = 4 VGPRs
typedef __attribute__((ext_vector_type(16))) float f32x16;  // MFMA 32x32 acc
typedef __attribute__((ext_vector_type(4))) int   i32x4;    // CSR record
typedef __attribute__((ext_vector_type(4))) float f32x4;
typedef __attribute__((ext_vector_type(2))) uint  u32x2;

__device__ inline float bflo(uint u) {
    union { uint x; float f; } z; z.x = u << 16; return z.f;
}
__device__ inline float bfhi(uint u) {
    union { uint x; float f; } z; z.x = u & 0xffff0000u; return z.f;
}
__device__ inline ushort f2bf(float f) {
    union { float f; uint u; } x; x.f = f;
    uint r = (x.u + 0x7fffu + ((x.u >> 16) & 1u)) >> 16;
    return (ushort)r;
}

// ---------------------------------------------------------------------------
// pack_x: x (fp32 row-major) -> bf16 fragment-ordered tiles:
//   xfrag chunk index o = tile*2048 + kb*128 + m   (chunk = 16B = 8 bf16)
//   holds x[tile*128+m][kb*8 .. kb*8+8), zero-padded past n rows.
// ---------------------------------------------------------------------------
__global__ __launch_bounds__(256) void pack_x(const float* __restrict__ x,
                                              uint4* __restrict__ xfrag,
                                              int n, int nchunks)
{
    int o = blockIdx.x * 256 + threadIdx.x;
    if (o >= nchunks) return;
    int m    = o & 127;
    int kb   = (o >> 7) & 15;
    int tile = o >> 11;
    int row  = tile * 128 + m;
    float4 lo = make_float4(0.f, 0.f, 0.f, 0.f);
    float4 hi = make_float4(0.f, 0.f, 0.f, 0.f);
    if (row < n) {
        lo = *(const float4*)&x[(size_t)row * 128 + kb * 8];
        hi = *(const float4*)&x[(size_t)row * 128 + kb * 8 + 4];
    }
    uint4 ov;
    ov.x = (uint)f2bf(lo.x) | ((uint)f2bf(lo.y) << 16);
    ov.y = (uint)f2bf(lo.z) | ((uint)f2bf(lo.w) << 16);
    ov.z = (uint)f2bf(hi.x) | ((uint)f2bf(hi.y) << 16);
    ov.w = (uint)f2bf(hi.z) | ((uint)f2bf(hi.w) << 16);
    xfrag[o] = ov;
}

// ---------------------------------------------------------------------------
// pack_w: W_j (fp32 [K=128][N=128] row-major) -> bf16 B-fragment order for
// j=0..3 (Wq,Wk,Wv,Wskip).  Section j=4 (chunks 8192..10239) computes the
// FOLDED t-projection Wt[k, h*16+d] = sum_c Wq[k,h*32+c]*We[d,h*32+c]
// (cols 64..127 zero) and bt, so t = x@Wt + bt rides the main MFMA kernel.
// ---------------------------------------------------------------------------
__global__ __launch_bounds__(256) void pack_w(
    const float* __restrict__ W0, const float* __restrict__ W1,
    const float* __restrict__ W2, const float* __restrict__ W3,
    const float* __restrict__ We, const float* __restrict__ bq,
    uint4* __restrict__ wfrag, float* __restrict__ btbuf)
{
    int o = blockIdx.x * 256 + threadIdx.x;   // 5*16*128 = 10240 chunks
    if (o >= 10240) return;
    float v[8];
    if (o < 8192) {
        int nn = o & 127;
        int kb = (o >> 7) & 15;
        int j  = o >> 11;
        const float* W = (j == 0) ? W0 : (j == 1) ? W1 : (j == 2) ? W2 : W3;
        #pragma unroll
        for (int i = 0; i < 8; ++i) v[i] = W[(size_t)(kb * 8 + i) * 128 + nn];
    } else {
        int o2 = o - 8192;
        int nn = o2 & 127;
        int kb = (o2 >> 7) & 15;
        #pragma unroll
        for (int i = 0; i < 8; ++i) v[i] = 0.f;
        if (nn < 64) {
            int h = nn >> 4, d = nn & 15;
            const float* wq = W0 + h * 32;          // Wq[k][h*32 + c]
            const float* we = We + (size_t)d * 128 + h * 32;
            #pragma unroll
            for (int i = 0; i < 8; ++i) {
                int k = kb * 8 + i;
                float s = 0.f;
                for (int c = 0; c < 32; ++c)
                    s += wq[(size_t)k * 128 + c] * we[c];
                v[i] = s;
            }
            if (kb == 0) {
                float s = 0.f;
                for (int c = 0; c < 32; ++c) s += bq[h * 32 + c] * we[c];
                btbuf[nn] = s;
            }
        }
    }
    uint4 ov;
    ov.x = (uint)f2bf(v[0]) | ((uint)f2bf(v[1]) << 16);
    ov.y = (uint)f2bf(v[2]) | ((uint)f2bf(v[3]) << 16);
    ov.z = (uint)f2bf(v[4]) | ((uint)f2bf(v[5]) << 16);
    ov.w = (uint)f2bf(v[6]) | ((uint)f2bf(v[7]) << 16);
    wfrag[o] = ov;
}

// ---------------------------------------------------------------------------
// lin_mfma: per block, 128 rows x 5 weight matrices (576 cols), K=128.
// v_mfma_f32_32x32x16_bf16; C/D: col=lane&31, row=(reg&3)+8*(reg>>2)+4*(lane>>5).
// Outputs bf16-pair packed: q [n][64], kv [n][128] (k 0..63 | v 64..127),
// skip [n][64], t [n][32]  (t = x@Wt+bt, 64 cols).
// ---------------------------------------------------------------------------
__global__ __launch_bounds__(256) void lin_mfma(
    const uint4* __restrict__ xfrag, const uint4* __restrict__ wfrag,
    const float* __restrict__ bq, const float* __restrict__ bk,
    const float* __restrict__ bv, const float* __restrict__ bs,
    const float* __restrict__ bt,
    uint* __restrict__ qout, uint* __restrict__ kvout, uint* __restrict__ sout,
    uint* __restrict__ tout, int n)
{
    const int tile = blockIdx.x;
    const int w  = threadIdx.x >> 6;
    const int l  = threadIdx.x & 63;
    const int lm = l & 31, lh = l >> 5;

    bf16x8 a[8];
    const uint4* ap = xfrag + (size_t)tile * 2048 + lh * 128 + w * 32 + lm;
    #pragma unroll
    for (int ks = 0; ks < 8; ++ks) a[ks] = *(const bf16x8*)(ap + ks * 256);

    const int rowbase = tile * 128 + w * 32 + 4 * lh;

    #pragma unroll
    for (int j = 0; j < 5; ++j) {
        const float* bias = (j == 0) ? bq : (j == 1) ? bk : (j == 2) ? bv
                          : (j == 3) ? bs : bt;
        uint* dst; int stride, cbase;
        if (j == 0)      { dst = qout;  stride = 64;  cbase = 0;  }
        else if (j == 1) { dst = kvout; stride = 128; cbase = 0;  }
        else if (j == 2) { dst = kvout; stride = 128; cbase = 64; }
        else if (j == 3) { dst = sout;  stride = 64;  cbase = 0;  }
        else             { dst = tout;  stride = 32;  cbase = 0;  }
        const int npc = (j == 4) ? 1 : 2;

        #pragma unroll
        for (int np = 0; np < npc; ++np) {       // ni pair {2np, 2np+1}
            const uint4* bp0 = wfrag + (size_t)j * 2048 + lh * 128 + (np * 2) * 32 + lm;
            f32x16 c0, c1;
            #pragma unroll
            for (int i = 0; i < 16; ++i) { c0[i] = 0.f; c1[i] = 0.f; }
            #pragma unroll
            for (int ks = 0; ks < 8; ++ks) {
                bf16x8 B0 = *(const bf16x8*)(bp0 + ks * 256);
                bf16x8 B1 = *(const bf16x8*)(bp0 + 32 + ks * 256);
                c0 = __builtin_amdgcn_mfma_f32_32x32x16_bf16(a[ks], B0, c0, 0, 0, 0);
                c1 = __builtin_amdgcn_mfma_f32_32x32x16_bf16(a[ks], B1, c1, 0, 0, 0);
            }
            #pragma unroll
            for (int t = 0; t < 2; ++t) {
                f32x16 cc = t ? c1 : c0;
                int gc = (np * 2 + t) * 32 + lm;
                float bl = bias[gc];
                #pragma unroll
                for (int r = 0; r < 16; ++r) {
                    float val = cc[r] + bl;
                    float partner = __shfl_xor(val, 1);
                    int gr = rowbase + (r & 3) + 8 * (r >> 2);
                    if (!(lm & 1) && gr < n) {
                        uint pk = (uint)f2bf(val) | ((uint)f2bf(partner) << 16);
                        dst[(size_t)gr * stride + cbase + (gc >> 1)] = pk;
                    }
                }
            }
        }
    }
}

// ---------------------------------------------------------------------------
// hist_g: per-edge rank assignment (contended device atomic) FUSED with the
// edge-logit precompute  g[h] = sum_d ea[e,d] * t[row_e, h, d].
// The ea stream (NT) + tb gather + 64 FMAs have no dependency on the atomic
// and execute inside its latency shadow — previously this work sat in
// scatter_g where it serialized behind nothing but still cost a full pass.
// Outputs: rank[i] (4B) + gbuf[i] = {bf16(g0,g1), bf16(g2,g3)} (8B), both
// coalesced edge-order streams.
// ---------------------------------------------------------------------------
__global__ __launch_bounds__(256) void hist_g_kernel(
    const int* __restrict__ rows, const float* __restrict__ ea,
    const uint* __restrict__ tb, int* __restrict__ counts,
    int* __restrict__ rank, u32x2* __restrict__ gbuf, int e)
{
    int i = blockIdx.x * blockDim.x + threadIdx.x;
    if (i >= e) return;
    int r = rows[i];
    int rk = atomicAdd(&counts[r], 1);   // issue early; g-work hides latency

    const f32x4* ep = (const f32x4*)&ea[(size_t)i * 16];
    f32x4 e0 = __builtin_nontemporal_load(ep);
    f32x4 e1 = __builtin_nontemporal_load(ep + 1);
    f32x4 e2 = __builtin_nontemporal_load(ep + 2);
    f32x4 e3 = __builtin_nontemporal_load(ep + 3);
    const uint* tp = tb + (size_t)r * 32;
    float g[4];
    #pragma unroll
    for (int h = 0; h < 4; ++h) {
        uint4 ua = *(const uint4*)(tp + h * 8);
        uint4 ub = *(const uint4*)(tp + h * 8 + 4);
        g[h] = e0[0] * bflo(ua.x) + e0[1] * bfhi(ua.x)
             + e0[2] * bflo(ua.y) + e0[3] * bfhi(ua.y)
             + e1[0] * bflo(ua.z) + e1[1] * bfhi(ua.z)
             + e1[2] * bflo(ua.w) + e1[3] * bfhi(ua.w)
             + e2[0] * bflo(ub.x) + e2[1] * bfhi(ub.x)
             + e2[2] * bflo(ub.y) + e2[3] * bfhi(ub.y)
             + e3[0] * bflo(ub.z) + e3[1] * bfhi(ub.z)
             + e3[2] * bflo(ub.w) + e3[3] * bfhi(ub.w);
    }
    u32x2 gp;
    gp.x = (uint)f2bf(g[0]) | ((uint)f2bf(g[1]) << 16);
    gp.y = (uint)f2bf(g[2]) | ((uint)f2bf(g[3]) << 16);
    gbuf[i] = gp;
    rank[i] = rk;
}

__global__ __launch_bounds__(1024) void scan1_kernel(int* __restrict__ data,
                                                     int* __restrict__ bsum, int n)
{
    __shared__ int s[1024];
    int i = blockIdx.x * 1024 + threadIdx.x;
    int v = (i < n) ? data[i] : 0;
    s[threadIdx.x] = v;
    __syncthreads();
    for (int offd = 1; offd < 1024; offd <<= 1) {
        int add = (threadIdx.x >= offd) ? s[threadIdx.x - offd] : 0;
        __syncthreads();
        s[threadIdx.x] += add;
        __syncthreads();
    }
    if (i < n) data[i] = s[threadIdx.x];
    if (threadIdx.x == 1023) bsum[blockIdx.x] = s[1023];
}

// fused scan2+scan3: every block redoes the (cheap) 1024-wide scan of bsum
// in LDS and picks its own exclusive prefix; then emits offsets.
__global__ __launch_bounds__(1024) void scan23_kernel(const int* __restrict__ incl,
                                                      const int* __restrict__ bsum,
                                                      int* __restrict__ offsets,
                                                      int n, int nb)
{
    __shared__ int s[1024];
    int tid = threadIdx.x;
    int v = (tid < nb) ? bsum[tid] : 0;
    s[tid] = v;
    __syncthreads();
    for (int o = 1; o < 1024; o <<= 1) {
        int add = (tid >= o) ? s[tid - o] : 0;
        __syncthreads();
        s[tid] += add;
        __syncthreads();
    }
    int bofs = (blockIdx.x == 0) ? 0 : s[blockIdx.x - 1];
    int i = blockIdx.x * 1024 + tid;
    if (i == 0) offsets[0] = 0;
    if (i < n) offsets[i + 1] = incl[i] + bofs;
}

// ---------------------------------------------------------------------------
// scatter: pure permutation now. Read {rows, cols, rank, gbuf} (24B coalesced)
// -> NT-store 16B CSR record {src, 0, g01, g23} at offsets[r]+rank.
// ---------------------------------------------------------------------------
__global__ __launch_bounds__(256) void scatter_kernel(
    const int* __restrict__ rows, const int* __restrict__ cols,
    const int* __restrict__ rank, const u32x2* __restrict__ gbuf,
    const int* __restrict__ offsets, i32x4* __restrict__ csr, int e)
{
    int i = blockIdx.x * blockDim.x + threadIdx.x;
    if (i >= e) return;
    int r = rows[i];
    int pos = offsets[r] + rank[i];
    u32x2 g = gbuf[i];
    i32x4 rec;
    rec.x = cols[i];
    rec.y = 0;
    rec.z = (int)g.x;
    rec.w = (int)g.y;
    __builtin_nontemporal_store(rec, &csr[pos]);
}

// ---------------------------------------------------------------------------
// Aggregation: one wave per destination node, 4 edges in parallel.
// lane = es*16 + h*4 + cq. Lane owns channels c0 = h*32+cq*8 .. +8 of its
// edge slot. The ea@We logit term arrives as bf16 g in the CSR record.
// csr is read-once -> non-temporal, keeps kv (gathered) resident in L2.
// ---------------------------------------------------------------------------
__global__ __launch_bounds__(256) void agg_kernel(
    const uint* __restrict__ qb, const uint* __restrict__ kv,
    const uint* __restrict__ sb, const i32x4* __restrict__ csr,
    const int* __restrict__ offsets, const float* __restrict__ Wbeta,
    float* __restrict__ out, int n)
{
    int wid = (blockIdx.x * blockDim.x + threadIdx.x) >> 6;
    int lane = threadIdx.x & 63;
    if (wid >= n) return;
    const int es = lane >> 4;
    const int h  = (lane >> 2) & 3;
    const int cq = lane & 3;
    const int c0 = h * 32 + cq * 8;

    uint4 uq = *(const uint4*)&qb[(size_t)wid * 64 + h * 16 + cq * 4];
    float qv[8] = { bflo(uq.x), bfhi(uq.x), bflo(uq.y), bfhi(uq.y),
                    bflo(uq.z), bfhi(uq.z), bflo(uq.w), bfhi(uq.w) };

    const int beg = offsets[wid], end = offsets[wid + 1];
    const float scale = 0.17677669529663687f;  // 1/sqrt(32)

    float denom = 0.f;
    float acc[8];
    #pragma unroll
    for (int j = 0; j < 8; ++j) acc[j] = 0.f;

    for (int i = beg; i < end; i += 4) {
        int idx = i + es;
        bool valid = idx < end;
        int cidx = valid ? idx : end - 1;
        i32x4 se = __builtin_nontemporal_load(&csr[cidx]);
        uint gp = (h & 2) ? (uint)se.w : (uint)se.z;
        float gh = (h & 1) ? bfhi(gp) : bflo(gp);
        const uint* krow = kv + (size_t)se.x * 128 + h * 16 + cq * 4;
        uint4 kp = *(const uint4*)krow;
        uint4 vp = *(const uint4*)(krow + 64);

        float part = qv[0] * bflo(kp.x) + qv[1] * bfhi(kp.x)
                   + qv[2] * bflo(kp.y) + qv[3] * bfhi(kp.y)
                   + qv[4] * bflo(kp.z) + qv[5] * bfhi(kp.z)
                   + qv[6] * bflo(kp.w) + qv[7] * bfhi(kp.w);
        part += __shfl_xor(part, 1);
        part += __shfl_xor(part, 2);
        float p = valid ? __expf((part + gh) * scale) : 0.f;
        denom += p;
        acc[0] += p * bflo(vp.x); acc[1] += p * bfhi(vp.x);
        acc[2] += p * bflo(vp.y); acc[3] += p * bfhi(vp.y);
        acc[4] += p * bflo(vp.z); acc[5] += p * bfhi(vp.z);
        acc[6] += p * bflo(vp.w); acc[7] += p * bfhi(vp.w);
    }

    denom += __shfl_xor(denom, 16);
    denom += __shfl_xor(denom, 32);
    #pragma unroll
    for (int j = 0; j < 8; ++j) {
        acc[j] += __shfl_xor(acc[j], 16);
        acc[j] += __shfl_xor(acc[j], 32);
    }

    float inv = 1.f / (denom + 1e-16f);
    float o[8];
    #pragma unroll
    for (int j = 0; j < 8; ++j) o[j] = acc[j] * inv;

    uint4 us = *(const uint4*)&sb[(size_t)wid * 64 + h * 16 + cq * 4];
    float xsv[8] = { bflo(us.x), bfhi(us.x), bflo(us.y), bfhi(us.y),
                     bflo(us.z), bfhi(us.z), bflo(us.w), bfhi(us.w) };

    float bp = 0.f;
    #pragma unroll
    for (int j = 0; j < 8; ++j) {
        bp += o[j]   * Wbeta[c0 + j]
            + xsv[j] * Wbeta[128 + c0 + j]
            + (o[j] - xsv[j]) * Wbeta[256 + c0 + j];
    }
    bp += __shfl_xor(bp, 1);
    bp += __shfl_xor(bp, 2);
    bp += __shfl_xor(bp, 4);
    bp += __shfl_xor(bp, 8);
    float beta = 1.f / (1.f + __expf(-bp));

    if (es == 0) {
        float r[8];
        #pragma unroll
        for (int j = 0; j < 8; ++j) r[j] = beta * xsv[j] + (1.f - beta) * o[j];
        f32x4 r0 = { r[0], r[1], r[2], r[3] };
        f32x4 r1 = { r[4], r[5], r[6], r[7] };
        __builtin_nontemporal_store(r0, (f32x4*)&out[(size_t)wid * 128 + c0]);
        __builtin_nontemporal_store(r1, (f32x4*)&out[(size_t)wid * 128 + c0 + 4]);
    }
}

// ---------------------------------------------------------------------------
extern "C" void kernel_launch(void* const* d_in, const int* in_sizes, int n_in,
                              void* d_out, int out_size, void* d_ws, size_t ws_size,
                              hipStream_t stream)
{
    const float* x     = (const float*)d_in[0];
    const float* ea    = (const float*)d_in[1];
    const int*   ei    = (const int*)d_in[2];   // [0:E)=row(dst), [E:2E)=col(src)
    const float* Wq    = (const float*)d_in[3];
    const float* bq    = (const float*)d_in[4];
    const float* Wk    = (const float*)d_in[5];
    const float* bk    = (const float*)d_in[6];
    const float* Wv    = (const float*)d_in[7];
    const float* bv    = (const float*)d_in[8];
    const float* We    = (const float*)d_in[9];
    const float* Wsk   = (const float*)d_in[10];
    const float* bsk   = (const float*)d_in[11];
    const float* Wbeta = (const float*)d_in[12];
    float* out = (float*)d_out;

    const int N = in_sizes[0] / 128;
    const int E = in_sizes[1] / 16;
    const int NT = (N + 127) / 128;         // 128-row tiles
    const int nchunks = NT * 2048;

    char* base = (char*)d_ws;
    size_t off = 0;
    auto alloc = [&](size_t bytes) -> void* {
        void* p = base + off;
        off += (bytes + 255) & ~(size_t)255;
        return p;
    };
    int*    tmp     = (int*)alloc((size_t)N * 4);
    int*    offsets = (int*)alloc((size_t)(N + 1) * 4);
    int*    bsum    = (int*)alloc(4096 * 4);
    int*    rank    = (int*)alloc((size_t)E * 4);
    u32x2*  gbuf    = (u32x2*)alloc((size_t)E * 8);
    float*  btbuf   = (float*)alloc(256);
    // xfrag is dead after lin_mfma; csr (written by scatter, later) aliases it.
    size_t  xfrag_bytes = (size_t)nchunks * 16;
    size_t  csr_bytes   = (size_t)E * 16;
    char*   shared_reg  = (char*)alloc(xfrag_bytes > csr_bytes ? xfrag_bytes : csr_bytes);
    uint4*  xfrag   = (uint4*)shared_reg;
    i32x4*  csr     = (i32x4*)shared_reg;
    uint4*  wfrag   = (uint4*)alloc((size_t)10240 * 16);  // 5 matrices
    uint*   qbuf    = (uint*)alloc((size_t)N * 64 * 4);   // bf16 pairs
    uint*   sbuf    = (uint*)alloc((size_t)N * 64 * 4);   // bf16 pairs
    uint*   tbuf    = (uint*)alloc((size_t)N * 32 * 4);   // bf16 pairs [n][h*8+d/2]
    uint*   kvbuf   = (uint*)alloc((size_t)N * 128 * 4);  // bf16: k [0..63], v [64..127]
    (void)ws_size; (void)n_in; (void)out_size;

    hipMemsetAsync(tmp, 0, (size_t)N * 4, stream);

    pack_x<<<(nchunks + 255) / 256, 256, 0, stream>>>(x, xfrag, N, nchunks);
    pack_w<<<40, 256, 0, stream>>>(Wq, Wk, Wv, Wsk, We, bq, wfrag, btbuf);
    lin_mfma<<<NT, 256, 0, stream>>>(xfrag, wfrag, bq, bk, bv, bsk, btbuf,
                                     qbuf, kvbuf, sbuf, tbuf, N);
    hist_g_kernel<<<(E + 255) / 256, 256, 0, stream>>>(ei, ea, tbuf, tmp,
                                                       rank, gbuf, E);
    int nb = (N + 1023) / 1024;
    scan1_kernel<<<nb, 1024, 0, stream>>>(tmp, bsum, N);
    scan23_kernel<<<nb, 1024, 0, stream>>>(tmp, bsum, offsets, N, nb);
    scatter_kernel<<<(E + 255) / 256, 256, 0, stream>>>(ei, ei + E, rank, gbuf,
                                                        offsets, csr, E);
    agg_kernel<<<(N + 3) / 4, 256, 0, stream>>>(qbuf, kvbuf, sbuf, csr,
                                                offsets, Wbeta, out, N);
}

// Round 7
// 577.437 us; speedup vs baseline: 1.2076x; 1.0111x over previous
//
#include <hip/hip_runtime.h>
#include <stdint.h>

typedef unsigned int uint;
typedef unsigned short ushort;

typedef __attribute__((ext_vector_type(8))) short bf16x8;   // 8 bf16 = 4 VGPRs
typedef __attribute__((ext_vector_type(16))) float f32x16;  // MFMA 32x32 acc
typedef __attribute__((ext_vector_type(4))) int   i32x4;    // CSR record
typedef __attribute__((ext_vector_type(4))) float f32x4;
typedef __attribute__((ext_vector_type(2))) uint  u32x2;

__device__ inline float bflo(uint u) {
    union { uint x; float f; } z; z.x = u << 16; return z.f;
}
__device__ inline float bfhi(uint u) {
    union { uint x; float f; } z; z.x = u & 0xffff0000u; return z.f;
}
__device__ inline ushort f2bf(float f) {
    union { float f; uint u; } x; x.f = f;
    uint r = (x.u + 0x7fffu + ((x.u >> 16) & 1u)) >> 16;
    return (ushort)r;
}

// ---------------------------------------------------------------------------
// pack_x: x (fp32 row-major) -> bf16 fragment-ordered tiles:
//   xfrag chunk index o = tile*2048 + kb*128 + m   (chunk = 16B = 8 bf16)
//   holds x[tile*128+m][kb*8 .. kb*8+8), zero-padded past n rows.
// ---------------------------------------------------------------------------
__global__ __launch_bounds__(256) void pack_x(const float* __restrict__ x,
                                              uint4* __restrict__ xfrag,
                                              int n, int nchunks)
{
    int o = blockIdx.x * 256 + threadIdx.x;
    if (o >= nchunks) return;
    int m    = o & 127;
    int kb   = (o >> 7) & 15;
    int tile = o >> 11;
    int row  = tile * 128 + m;
    float4 lo = make_float4(0.f, 0.f, 0.f, 0.f);
    float4 hi = make_float4(0.f, 0.f, 0.f, 0.f);
    if (row < n) {
        lo = *(const float4*)&x[(size_t)row * 128 + kb * 8];
        hi = *(const float4*)&x[(size_t)row * 128 + kb * 8 + 4];
    }
    uint4 ov;
    ov.x = (uint)f2bf(lo.x) | ((uint)f2bf(lo.y) << 16);
    ov.y = (uint)f2bf(lo.z) | ((uint)f2bf(lo.w) << 16);
    ov.z = (uint)f2bf(hi.x) | ((uint)f2bf(hi.y) << 16);
    ov.w = (uint)f2bf(hi.z) | ((uint)f2bf(hi.w) << 16);
    xfrag[o] = ov;
}

// ---------------------------------------------------------------------------
// pack_w: W_j (fp32 [K=128][N=128] row-major) -> bf16 B-fragment order for
// j=0..3 (Wq,Wk,Wv,Wskip).  Section j=4 (chunks 8192..10239) computes the
// FOLDED t-projection Wt[k, h*16+d] = sum_c Wq[k,h*32+c]*We[d,h*32+c]
// (cols 64..127 zero) and bt, so t = x@Wt + bt rides the main MFMA kernel.
// ---------------------------------------------------------------------------
__global__ __launch_bounds__(256) void pack_w(
    const float* __restrict__ W0, const float* __restrict__ W1,
    const float* __restrict__ W2, const float* __restrict__ W3,
    const float* __restrict__ We, const float* __restrict__ bq,
    uint4* __restrict__ wfrag, float* __restrict__ btbuf)
{
    int o = blockIdx.x * 256 + threadIdx.x;   // 5*16*128 = 10240 chunks
    if (o >= 10240) return;
    float v[8];
    if (o < 8192) {
        int nn = o & 127;
        int kb = (o >> 7) & 15;
        int j  = o >> 11;
        const float* W = (j == 0) ? W0 : (j == 1) ? W1 : (j == 2) ? W2 : W3;
        #pragma unroll
        for (int i = 0; i < 8; ++i) v[i] = W[(size_t)(kb * 8 + i) * 128 + nn];
    } else {
        int o2 = o - 8192;
        int nn = o2 & 127;
        int kb = (o2 >> 7) & 15;
        #pragma unroll
        for (int i = 0; i < 8; ++i) v[i] = 0.f;
        if (nn < 64) {
            int h = nn >> 4, d = nn & 15;
            const float* wq = W0 + h * 32;          // Wq[k][h*32 + c]
            const float* we = We + (size_t)d * 128 + h * 32;
            #pragma unroll
            for (int i = 0; i < 8; ++i) {
                int k = kb * 8 + i;
                float s = 0.f;
                for (int c = 0; c < 32; ++c)
                    s += wq[(size_t)k * 128 + c] * we[c];
                v[i] = s;
            }
            if (kb == 0) {
                float s = 0.f;
                for (int c = 0; c < 32; ++c) s += bq[h * 32 + c] * we[c];
                btbuf[nn] = s;
            }
        }
    }
    uint4 ov;
    ov.x = (uint)f2bf(v[0]) | ((uint)f2bf(v[1]) << 16);
    ov.y = (uint)f2bf(v[2]) | ((uint)f2bf(v[3]) << 16);
    ov.z = (uint)f2bf(v[4]) | ((uint)f2bf(v[5]) << 16);
    ov.w = (uint)f2bf(v[6]) | ((uint)f2bf(v[7]) << 16);
    wfrag[o] = ov;
}

// ---------------------------------------------------------------------------
// lin_mfma: per block, 128 rows x 5 weight matrices (576 cols), K=128.
// v_mfma_f32_32x32x16_bf16; C/D: col=lane&31, row=(reg&3)+8*(reg>>2)+4*(lane>>5).
// Outputs bf16-pair packed: q [n][64], kv [n][128] (k 0..63 | v 64..127),
// skip [n][64], t [n][32]  (t = x@Wt+bt, 64 cols).
// ---------------------------------------------------------------------------
__global__ __launch_bounds__(256) void lin_mfma(
    const uint4* __restrict__ xfrag, const uint4* __restrict__ wfrag,
    const float* __restrict__ bq, const float* __restrict__ bk,
    const float* __restrict__ bv, const float* __restrict__ bs,
    const float* __restrict__ bt,
    uint* __restrict__ qout, uint* __restrict__ kvout, uint* __restrict__ sout,
    uint* __restrict__ tout, int n)
{
    const int tile = blockIdx.x;
    const int w  = threadIdx.x >> 6;
    const int l  = threadIdx.x & 63;
    const int lm = l & 31, lh = l >> 5;

    bf16x8 a[8];
    const uint4* ap = xfrag + (size_t)tile * 2048 + lh * 128 + w * 32 + lm;
    #pragma unroll
    for (int ks = 0; ks < 8; ++ks) a[ks] = *(const bf16x8*)(ap + ks * 256);

    const int rowbase = tile * 128 + w * 32 + 4 * lh;

    #pragma unroll
    for (int j = 0; j < 5; ++j) {
        const float* bias = (j == 0) ? bq : (j == 1) ? bk : (j == 2) ? bv
                          : (j == 3) ? bs : bt;
        uint* dst; int stride, cbase;
        if (j == 0)      { dst = qout;  stride = 64;  cbase = 0;  }
        else if (j == 1) { dst = kvout; stride = 128; cbase = 0;  }
        else if (j == 2) { dst = kvout; stride = 128; cbase = 64; }
        else if (j == 3) { dst = sout;  stride = 64;  cbase = 0;  }
        else             { dst = tout;  stride = 32;  cbase = 0;  }
        const int npc = (j == 4) ? 1 : 2;

        #pragma unroll
        for (int np = 0; np < npc; ++np) {       // ni pair {2np, 2np+1}
            const uint4* bp0 = wfrag + (size_t)j * 2048 + lh * 128 + (np * 2) * 32 + lm;
            f32x16 c0, c1;
            #pragma unroll
            for (int i = 0; i < 16; ++i) { c0[i] = 0.f; c1[i] = 0.f; }
            #pragma unroll
            for (int ks = 0; ks < 8; ++ks) {
                bf16x8 B0 = *(const bf16x8*)(bp0 + ks * 256);
                bf16x8 B1 = *(const bf16x8*)(bp0 + 32 + ks * 256);
                c0 = __builtin_amdgcn_mfma_f32_32x32x16_bf16(a[ks], B0, c0, 0, 0, 0);
                c1 = __builtin_amdgcn_mfma_f32_32x32x16_bf16(a[ks], B1, c1, 0, 0, 0);
            }
            #pragma unroll
            for (int t = 0; t < 2; ++t) {
                f32x16 cc = t ? c1 : c0;
                int gc = (np * 2 + t) * 32 + lm;
                float bl = bias[gc];
                #pragma unroll
                for (int r = 0; r < 16; ++r) {
                    float val = cc[r] + bl;
                    float partner = __shfl_xor(val, 1);
                    int gr = rowbase + (r & 3) + 8 * (r >> 2);
                    if (!(lm & 1) && gr < n) {
                        uint pk = (uint)f2bf(val) | ((uint)f2bf(partner) << 16);
                        dst[(size_t)gr * stride + cbase + (gc >> 1)] = pk;
                    }
                }
            }
        }
    }
}

// ---------------------------------------------------------------------------
// hist_g: per-edge rank assignment (contended device atomic) FUSED with the
// edge-logit precompute  g[h] = sum_d ea[e,d] * t[row_e, h, d].
// Outputs: rank[i] (4B) + gbuf[i] (8B), coalesced edge-order streams.
// ---------------------------------------------------------------------------
__global__ __launch_bounds__(256) void hist_g_kernel(
    const int* __restrict__ rows, const float* __restrict__ ea,
    const uint* __restrict__ tb, int* __restrict__ counts,
    int* __restrict__ rank, u32x2* __restrict__ gbuf, int e)
{
    int i = blockIdx.x * blockDim.x + threadIdx.x;
    if (i >= e) return;
    int r = rows[i];
    int rk = atomicAdd(&counts[r], 1);   // issue early; g-work hides latency

    const f32x4* ep = (const f32x4*)&ea[(size_t)i * 16];
    f32x4 e0 = __builtin_nontemporal_load(ep);
    f32x4 e1 = __builtin_nontemporal_load(ep + 1);
    f32x4 e2 = __builtin_nontemporal_load(ep + 2);
    f32x4 e3 = __builtin_nontemporal_load(ep + 3);
    const uint* tp = tb + (size_t)r * 32;
    float g[4];
    #pragma unroll
    for (int h = 0; h < 4; ++h) {
        uint4 ua = *(const uint4*)(tp + h * 8);
        uint4 ub = *(const uint4*)(tp + h * 8 + 4);
        g[h] = e0[0] * bflo(ua.x) + e0[1] * bfhi(ua.x)
             + e0[2] * bflo(ua.y) + e0[3] * bfhi(ua.y)
             + e1[0] * bflo(ua.z) + e1[1] * bfhi(ua.z)
             + e1[2] * bflo(ua.w) + e1[3] * bfhi(ua.w)
             + e2[0] * bflo(ub.x) + e2[1] * bfhi(ub.x)
             + e2[2] * bflo(ub.y) + e2[3] * bfhi(ub.y)
             + e3[0] * bflo(ub.z) + e3[1] * bfhi(ub.z)
             + e3[2] * bflo(ub.w) + e3[3] * bfhi(ub.w);
    }
    u32x2 gp;
    gp.x = (uint)f2bf(g[0]) | ((uint)f2bf(g[1]) << 16);
    gp.y = (uint)f2bf(g[2]) | ((uint)f2bf(g[3]) << 16);
    gbuf[i] = gp;
    rank[i] = rk;
}

__global__ __launch_bounds__(1024) void scan1_kernel(int* __restrict__ data,
                                                     int* __restrict__ bsum, int n)
{
    __shared__ int s[1024];
    int i = blockIdx.x * 1024 + threadIdx.x;
    int v = (i < n) ? data[i] : 0;
    s[threadIdx.x] = v;
    __syncthreads();
    for (int offd = 1; offd < 1024; offd <<= 1) {
        int add = (threadIdx.x >= offd) ? s[threadIdx.x - offd] : 0;
        __syncthreads();
        s[threadIdx.x] += add;
        __syncthreads();
    }
    if (i < n) data[i] = s[threadIdx.x];
    if (threadIdx.x == 1023) bsum[blockIdx.x] = s[1023];
}

// fused scan2+scan3: every block redoes the (cheap) 1024-wide scan of bsum
// in LDS and picks its own exclusive prefix; then emits offsets.
__global__ __launch_bounds__(1024) void scan23_kernel(const int* __restrict__ incl,
                                                      const int* __restrict__ bsum,
                                                      int* __restrict__ offsets,
                                                      int n, int nb)
{
    __shared__ int s[1024];
    int tid = threadIdx.x;
    int v = (tid < nb) ? bsum[tid] : 0;
    s[tid] = v;
    __syncthreads();
    for (int o = 1; o < 1024; o <<= 1) {
        int add = (tid >= o) ? s[tid - o] : 0;
        __syncthreads();
        s[tid] += add;
        __syncthreads();
    }
    int bofs = (blockIdx.x == 0) ? 0 : s[blockIdx.x - 1];
    int i = blockIdx.x * 1024 + tid;
    if (i == 0) offsets[0] = 0;
    if (i < n) offsets[i + 1] = incl[i] + bofs;
}

// ---------------------------------------------------------------------------
// scatter: pure permutation. Read {rows, cols, rank, gbuf} (24B coalesced)
// -> NT-store 16B CSR record {src, 0, g01, g23} at offsets[r]+rank.
// ---------------------------------------------------------------------------
__global__ __launch_bounds__(256) void scatter_kernel(
    const int* __restrict__ rows, const int* __restrict__ cols,
    const int* __restrict__ rank, const u32x2* __restrict__ gbuf,
    const int* __restrict__ offsets, i32x4* __restrict__ csr, int e)
{
    int i = blockIdx.x * blockDim.x + threadIdx.x;
    if (i >= e) return;
    int r = rows[i];
    int pos = offsets[r] + rank[i];
    u32x2 g = gbuf[i];
    i32x4 rec;
    rec.x = cols[i];
    rec.y = 0;
    rec.z = (int)g.x;
    rec.w = (int)g.y;
    __builtin_nontemporal_store(rec, &csr[pos]);
}

// ---------------------------------------------------------------------------
// Aggregation: one wave per destination node, 8 edges in flight (2x unrolled
// over 4 edge slots). lane = es*16 + h*4 + cq; lane owns channels
// c0 = h*32+cq*8 .. +8 of its slot. Slots idx and idx+4 are issued together
// so two independent csr+k/v gather bundles overlap (MLP x2 — the loop was
// dependency-stall bound at VALUBusy 52%).
// ---------------------------------------------------------------------------
__global__ __launch_bounds__(256) void agg_kernel(
    const uint* __restrict__ qb, const uint* __restrict__ kv,
    const uint* __restrict__ sb, const i32x4* __restrict__ csr,
    const int* __restrict__ offsets, const float* __restrict__ Wbeta,
    float* __restrict__ out, int n)
{
    int wid = (blockIdx.x * blockDim.x + threadIdx.x) >> 6;
    int lane = threadIdx.x & 63;
    if (wid >= n) return;
    const int es = lane >> 4;
    const int h  = (lane >> 2) & 3;
    const int cq = lane & 3;
    const int c0 = h * 32 + cq * 8;

    uint4 uq = *(const uint4*)&qb[(size_t)wid * 64 + h * 16 + cq * 4];
    float qv[8] = { bflo(uq.x), bfhi(uq.x), bflo(uq.y), bfhi(uq.y),
                    bflo(uq.z), bfhi(uq.z), bflo(uq.w), bfhi(uq.w) };

    const int beg = offsets[wid], end = offsets[wid + 1];
    const float scale = 0.17677669529663687f;  // 1/sqrt(32)

    float denom = 0.f;
    float acc[8];
    #pragma unroll
    for (int j = 0; j < 8; ++j) acc[j] = 0.f;

    for (int i = beg; i < end; i += 8) {
        int idxA = i + es;
        int idxB = i + es + 4;
        bool vA = idxA < end;
        bool vB = idxB < end;
        int cA = vA ? idxA : end - 1;
        int cB = vB ? idxB : end - 1;
        i32x4 seA = __builtin_nontemporal_load(&csr[cA]);
        i32x4 seB = __builtin_nontemporal_load(&csr[cB]);
        const uint* krA = kv + (size_t)seA.x * 128 + h * 16 + cq * 4;
        const uint* krB = kv + (size_t)seB.x * 128 + h * 16 + cq * 4;
        uint4 kpA = *(const uint4*)krA;
        uint4 vpA = *(const uint4*)(krA + 64);
        uint4 kpB = *(const uint4*)krB;
        uint4 vpB = *(const uint4*)(krB + 64);

        uint gwA = (h & 2) ? (uint)seA.w : (uint)seA.z;
        float ghA = (h & 1) ? bfhi(gwA) : bflo(gwA);
        uint gwB = (h & 2) ? (uint)seB.w : (uint)seB.z;
        float ghB = (h & 1) ? bfhi(gwB) : bflo(gwB);

        float pa = qv[0] * bflo(kpA.x) + qv[1] * bfhi(kpA.x)
                 + qv[2] * bflo(kpA.y) + qv[3] * bfhi(kpA.y)
                 + qv[4] * bflo(kpA.z) + qv[5] * bfhi(kpA.z)
                 + qv[6] * bflo(kpA.w) + qv[7] * bfhi(kpA.w);
        float pb = qv[0] * bflo(kpB.x) + qv[1] * bfhi(kpB.x)
                 + qv[2] * bflo(kpB.y) + qv[3] * bfhi(kpB.y)
                 + qv[4] * bflo(kpB.z) + qv[5] * bfhi(kpB.z)
                 + qv[6] * bflo(kpB.w) + qv[7] * bfhi(kpB.w);
        pa += __shfl_xor(pa, 1);
        pa += __shfl_xor(pa, 2);
        pb += __shfl_xor(pb, 1);
        pb += __shfl_xor(pb, 2);
        float eA = vA ? __expf((pa + ghA) * scale) : 0.f;
        float eB = vB ? __expf((pb + ghB) * scale) : 0.f;
        denom += eA + eB;
        acc[0] += eA * bflo(vpA.x) + eB * bflo(vpB.x);
        acc[1] += eA * bfhi(vpA.x) + eB * bfhi(vpB.x);
        acc[2] += eA * bflo(vpA.y) + eB * bflo(vpB.y);
        acc[3] += eA * bfhi(vpA.y) + eB * bfhi(vpB.y);
        acc[4] += eA * bflo(vpA.z) + eB * bflo(vpB.z);
        acc[5] += eA * bfhi(vpA.z) + eB * bfhi(vpB.z);
        acc[6] += eA * bflo(vpA.w) + eB * bflo(vpB.w);
        acc[7] += eA * bfhi(vpA.w) + eB * bfhi(vpB.w);
    }

    denom += __shfl_xor(denom, 16);
    denom += __shfl_xor(denom, 32);
    #pragma unroll
    for (int j = 0; j < 8; ++j) {
        acc[j] += __shfl_xor(acc[j], 16);
        acc[j] += __shfl_xor(acc[j], 32);
    }

    float inv = 1.f / (denom + 1e-16f);
    float o[8];
    #pragma unroll
    for (int j = 0; j < 8; ++j) o[j] = acc[j] * inv;

    uint4 us = *(const uint4*)&sb[(size_t)wid * 64 + h * 16 + cq * 4];
    float xsv[8] = { bflo(us.x), bfhi(us.x), bflo(us.y), bfhi(us.y),
                     bflo(us.z), bfhi(us.z), bflo(us.w), bfhi(us.w) };

    f32x4 wb0a = *(const f32x4*)&Wbeta[c0];
    f32x4 wb0b = *(const f32x4*)&Wbeta[c0 + 4];
    f32x4 wb1a = *(const f32x4*)&Wbeta[128 + c0];
    f32x4 wb1b = *(const f32x4*)&Wbeta[128 + c0 + 4];
    f32x4 wb2a = *(const f32x4*)&Wbeta[256 + c0];
    f32x4 wb2b = *(const f32x4*)&Wbeta[256 + c0 + 4];

    float bp = 0.f;
    #pragma unroll
    for (int j = 0; j < 4; ++j) {
        bp += o[j]     * wb0a[j] + xsv[j]     * wb1a[j] + (o[j]     - xsv[j])     * wb2a[j];
        bp += o[j + 4] * wb0b[j] + xsv[j + 4] * wb1b[j] + (o[j + 4] - xsv[j + 4]) * wb2b[j];
    }
    bp += __shfl_xor(bp, 1);
    bp += __shfl_xor(bp, 2);
    bp += __shfl_xor(bp, 4);
    bp += __shfl_xor(bp, 8);
    float beta = 1.f / (1.f + __expf(-bp));

    if (es == 0) {
        float r[8];
        #pragma unroll
        for (int j = 0; j < 8; ++j) r[j] = beta * xsv[j] + (1.f - beta) * o[j];
        f32x4 r0 = { r[0], r[1], r[2], r[3] };
        f32x4 r1 = { r[4], r[5], r[6], r[7] };
        __builtin_nontemporal_store(r0, (f32x4*)&out[(size_t)wid * 128 + c0]);
        __builtin_nontemporal_store(r1, (f32x4*)&out[(size_t)wid * 128 + c0 + 4]);
    }
}

// ---------------------------------------------------------------------------
extern "C" void kernel_launch(void* const* d_in, const int* in_sizes, int n_in,
                              void* d_out, int out_size, void* d_ws, size_t ws_size,
                              hipStream_t stream)
{
    const float* x     = (const float*)d_in[0];
    const float* ea    = (const float*)d_in[1];
    const int*   ei    = (const int*)d_in[2];   // [0:E)=row(dst), [E:2E)=col(src)
    const float* Wq    = (const float*)d_in[3];
    const float* bq    = (const float*)d_in[4];
    const float* Wk    = (const float*)d_in[5];
    const float* bk    = (const float*)d_in[6];
    const float* Wv    = (const float*)d_in[7];
    const float* bv    = (const float*)d_in[8];
    const float* We    = (const float*)d_in[9];
    const float* Wsk   = (const float*)d_in[10];
    const float* bsk   = (const float*)d_in[11];
    const float* Wbeta = (const float*)d_in[12];
    float* out = (float*)d_out;

    const int N = in_sizes[0] / 128;
    const int E = in_sizes[1] / 16;
    const int NT = (N + 127) / 128;         // 128-row tiles
    const int nchunks = NT * 2048;

    char* base = (char*)d_ws;
    size_t off = 0;
    auto alloc = [&](size_t bytes) -> void* {
        void* p = base + off;
        off += (bytes + 255) & ~(size_t)255;
        return p;
    };
    int*    tmp     = (int*)alloc((size_t)N * 4);
    int*    offsets = (int*)alloc((size_t)(N + 1) * 4);
    int*    bsum    = (int*)alloc(4096 * 4);
    int*    rank    = (int*)alloc((size_t)E * 4);
    u32x2*  gbuf    = (u32x2*)alloc((size_t)E * 8);
    float*  btbuf   = (float*)alloc(256);
    // xfrag is dead after lin_mfma; csr (written by scatter, later) aliases it.
    size_t  xfrag_bytes = (size_t)nchunks * 16;
    size_t  csr_bytes   = (size_t)E * 16;
    char*   shared_reg  = (char*)alloc(xfrag_bytes > csr_bytes ? xfrag_bytes : csr_bytes);
    uint4*  xfrag   = (uint4*)shared_reg;
    i32x4*  csr     = (i32x4*)shared_reg;
    uint4*  wfrag   = (uint4*)alloc((size_t)10240 * 16);  // 5 matrices
    uint*   qbuf    = (uint*)alloc((size_t)N * 64 * 4);   // bf16 pairs
    uint*   sbuf    = (uint*)alloc((size_t)N * 64 * 4);   // bf16 pairs
    uint*   tbuf    = (uint*)alloc((size_t)N * 32 * 4);   // bf16 pairs [n][h*8+d/2]
    uint*   kvbuf   = (uint*)alloc((size_t)N * 128 * 4);  // bf16: k [0..63], v [64..127]
    (void)ws_size; (void)n_in; (void)out_size;

    hipMemsetAsync(tmp, 0, (size_t)N * 4, stream);

    pack_x<<<(nchunks + 255) / 256, 256, 0, stream>>>(x, xfrag, N, nchunks);
    pack_w<<<40, 256, 0, stream>>>(Wq, Wk, Wv, Wsk, We, bq, wfrag, btbuf);
    lin_mfma<<<NT, 256, 0, stream>>>(xfrag, wfrag, bq, bk, bv, bsk, btbuf,
                                     qbuf, kvbuf, sbuf, tbuf, N);
    hist_g_kernel<<<(E + 255) / 256, 256, 0, stream>>>(ei, ea, tbuf, tmp,
                                                       rank, gbuf, E);
    int nb = (N + 1023) / 1024;
    scan1_kernel<<<nb, 1024, 0, stream>>>(tmp, bsum, N);
    scan23_kernel<<<nb, 1024, 0, stream>>>(tmp, bsum, offsets, N, nb);
    scatter_kernel<<<(E + 255) / 256, 256, 0, stream>>>(ei, ei + E, rank, gbuf,
                                                        offsets, csr, E);
    agg_kernel<<<(N + 3) / 4, 256, 0, stream>>>(qbuf, kvbuf, sbuf, csr,
                                                offsets, Wbeta, out, N);
}

// Round 8
// 540.599 us; speedup vs baseline: 1.2899x; 1.0681x over previous
//
#include <hip/hip_runtime.h>
#include <stdint.h>

typedef unsigned int uint;
typedef unsigned short ushort;

typedef __attribute__((ext_vector_type(8))) short bf16x8;   // 8 bf16 = 4 VGPRs
typedef __attribute__((ext_vector_type(16))) float f32x16;  // MFMA 32x32 acc
typedef __attribute__((ext_vector_type(4))) int   i32x4;    // CSR record
typedef __attribute__((ext_vector_type(4))) float f32x4;
typedef __attribute__((ext_vector_type(2))) uint  u32x2;

__device__ inline float bflo(uint u) {
    union { uint x; float f; } z; z.x = u << 16; return z.f;
}
__device__ inline float bfhi(uint u) {
    union { uint x; float f; } z; z.x = u & 0xffff0000u; return z.f;
}
__device__ inline ushort f2bf(float f) {
    union { float f; uint u; } x; x.f = f;
    uint r = (x.u + 0x7fffu + ((x.u >> 16) & 1u)) >> 16;
    return (ushort)r;
}

// ---------------------------------------------------------------------------
// prep: fused pack_x + pack_w(+Wt fold) + counts-zero. All three regions are
// 256-aligned so the branch is block-uniform (no divergence).
//   [0, nchunks)                : pack_x   -> xfrag
//   [nchunks, nchunks+10240)    : pack_w   -> wfrag (5 matrices, j=4 = Wt fold)
//   [nchunks+10240, ... +N)     : counts[z] = 0
// ---------------------------------------------------------------------------
__global__ __launch_bounds__(256) void prep_kernel(
    const float* __restrict__ x, uint4* __restrict__ xfrag, int n, int nchunks,
    const float* __restrict__ W0, const float* __restrict__ W1,
    const float* __restrict__ W2, const float* __restrict__ W3,
    const float* __restrict__ We, const float* __restrict__ bq,
    uint4* __restrict__ wfrag, float* __restrict__ btbuf,
    int* __restrict__ counts)
{
    int o = blockIdx.x * 256 + threadIdx.x;
    if (o < nchunks) {
        int m    = o & 127;
        int kb   = (o >> 7) & 15;
        int tile = o >> 11;
        int row  = tile * 128 + m;
        float4 lo = make_float4(0.f, 0.f, 0.f, 0.f);
        float4 hi = make_float4(0.f, 0.f, 0.f, 0.f);
        if (row < n) {
            lo = *(const float4*)&x[(size_t)row * 128 + kb * 8];
            hi = *(const float4*)&x[(size_t)row * 128 + kb * 8 + 4];
        }
        uint4 ov;
        ov.x = (uint)f2bf(lo.x) | ((uint)f2bf(lo.y) << 16);
        ov.y = (uint)f2bf(lo.z) | ((uint)f2bf(lo.w) << 16);
        ov.z = (uint)f2bf(hi.x) | ((uint)f2bf(hi.y) << 16);
        ov.w = (uint)f2bf(hi.z) | ((uint)f2bf(hi.w) << 16);
        xfrag[o] = ov;
        return;
    }
    int ow = o - nchunks;
    if (ow < 10240) {
        float v[8];
        if (ow < 8192) {
            int nn = ow & 127;
            int kb = (ow >> 7) & 15;
            int j  = ow >> 11;
            const float* W = (j == 0) ? W0 : (j == 1) ? W1 : (j == 2) ? W2 : W3;
            #pragma unroll
            for (int i = 0; i < 8; ++i) v[i] = W[(size_t)(kb * 8 + i) * 128 + nn];
        } else {
            int o2 = ow - 8192;
            int nn = o2 & 127;
            int kb = (o2 >> 7) & 15;
            #pragma unroll
            for (int i = 0; i < 8; ++i) v[i] = 0.f;
            if (nn < 64) {
                int h = nn >> 4, d = nn & 15;
                const float* wq = W0 + h * 32;          // Wq[k][h*32 + c]
                const float* we = We + (size_t)d * 128 + h * 32;
                #pragma unroll
                for (int i = 0; i < 8; ++i) {
                    int k = kb * 8 + i;
                    float s = 0.f;
                    for (int c = 0; c < 32; ++c)
                        s += wq[(size_t)k * 128 + c] * we[c];
                    v[i] = s;
                }
                if (kb == 0) {
                    float s = 0.f;
                    for (int c = 0; c < 32; ++c) s += bq[h * 32 + c] * we[c];
                    btbuf[nn] = s;
                }
            }
        }
        uint4 ov;
        ov.x = (uint)f2bf(v[0]) | ((uint)f2bf(v[1]) << 16);
        ov.y = (uint)f2bf(v[2]) | ((uint)f2bf(v[3]) << 16);
        ov.z = (uint)f2bf(v[4]) | ((uint)f2bf(v[5]) << 16);
        ov.w = (uint)f2bf(v[6]) | ((uint)f2bf(v[7]) << 16);
        wfrag[ow] = ov;
        return;
    }
    int z = ow - 10240;
    if (z < n) counts[z] = 0;
}

// ---------------------------------------------------------------------------
// lin_mfma: per block, 128 rows x 5 weight matrices (576 cols), K=128.
// v_mfma_f32_32x32x16_bf16; C/D: col=lane&31, row=(reg&3)+8*(reg>>2)+4*(lane>>5).
// NEW epilogue: accumulators -> bf16 LDS tile [128][130] (pad=2 ushorts:
// b16 writes 2-way, uint4 reads 2-way -> conflict-free per N/2.8 rule),
// then 256 threads store full dwordx4 coalesced rows. Replaces the old
// 288-shfl + 288 half-masked-4B-store epilogue per wave.
// Outputs bf16-pair packed: q [n][64], kv [n][128] (k 0..63 | v 64..127),
// skip [n][64], t [n][32]  (t = x@Wt+bt, 64 cols).
// ---------------------------------------------------------------------------
__global__ __launch_bounds__(256) void lin_mfma(
    const uint4* __restrict__ xfrag, const uint4* __restrict__ wfrag,
    const float* __restrict__ bq, const float* __restrict__ bk,
    const float* __restrict__ bv, const float* __restrict__ bs,
    const float* __restrict__ bt,
    uint* __restrict__ qout, uint* __restrict__ kvout, uint* __restrict__ sout,
    uint* __restrict__ tout, int n)
{
    __shared__ ushort lt[128][130];   // 33.3 KB, +2 ushort row pad

    const int tile = blockIdx.x;
    const int w  = threadIdx.x >> 6;
    const int l  = threadIdx.x & 63;
    const int lm = l & 31, lh = l >> 5;

    bf16x8 a[8];
    const uint4* ap = xfrag + (size_t)tile * 2048 + lh * 128 + w * 32 + lm;
    #pragma unroll
    for (int ks = 0; ks < 8; ++ks) a[ks] = *(const bf16x8*)(ap + ks * 256);

    #pragma unroll
    for (int j = 0; j < 5; ++j) {
        const float* bias = (j == 0) ? bq : (j == 1) ? bk : (j == 2) ? bv
                          : (j == 3) ? bs : bt;
        uint* dst; int stride, cbase;
        if (j == 0)      { dst = qout;  stride = 64;  cbase = 0;  }
        else if (j == 1) { dst = kvout; stride = 128; cbase = 0;  }
        else if (j == 2) { dst = kvout; stride = 128; cbase = 64; }
        else if (j == 3) { dst = sout;  stride = 64;  cbase = 0;  }
        else             { dst = tout;  stride = 32;  cbase = 0;  }
        const int npc = (j == 4) ? 1 : 2;

        #pragma unroll
        for (int np = 0; np < npc; ++np) {       // ni pair {2np, 2np+1}
            const uint4* bp0 = wfrag + (size_t)j * 2048 + lh * 128 + (np * 2) * 32 + lm;
            f32x16 c0, c1;
            #pragma unroll
            for (int i = 0; i < 16; ++i) { c0[i] = 0.f; c1[i] = 0.f; }
            #pragma unroll
            for (int ks = 0; ks < 8; ++ks) {
                bf16x8 B0 = *(const bf16x8*)(bp0 + ks * 256);
                bf16x8 B1 = *(const bf16x8*)(bp0 + 32 + ks * 256);
                c0 = __builtin_amdgcn_mfma_f32_32x32x16_bf16(a[ks], B0, c0, 0, 0, 0);
                c1 = __builtin_amdgcn_mfma_f32_32x32x16_bf16(a[ks], B1, c1, 0, 0, 0);
            }
            #pragma unroll
            for (int t = 0; t < 2; ++t) {
                f32x16 cc = t ? c1 : c0;
                int gc = (np * 2 + t) * 32 + lm;
                float bl = bias[gc];
                #pragma unroll
                for (int r = 0; r < 16; ++r) {
                    int lr = w * 32 + 4 * lh + (r & 3) + 8 * (r >> 2);
                    lt[lr][gc] = f2bf(cc[r] + bl);
                }
            }
        }
        __syncthreads();
        if (j != 4) {
            // 128 cols bf16 = 64 uints = 16 chunks of 16B per row
            int ch = threadIdx.x & 15;
            int rr = threadIdx.x >> 4;          // 0..15
            #pragma unroll
            for (int g = 0; g < 8; ++g) {
                int row = g * 16 + rr;
                int gr = tile * 128 + row;
                if (gr < n) {
                    uint4 vls = *(const uint4*)&lt[row][ch * 8];
                    *(uint4*)(dst + (size_t)gr * stride + cbase + ch * 4) = vls;
                }
            }
        } else {
            // 64 cols bf16 = 32 uints = 8 chunks of 16B per row
            int ch = threadIdx.x & 7;
            int rr = threadIdx.x >> 3;          // 0..31
            #pragma unroll
            for (int g = 0; g < 4; ++g) {
                int row = g * 32 + rr;
                int gr = tile * 128 + row;
                if (gr < n) {
                    uint4 vls = *(const uint4*)&lt[row][ch * 8];
                    *(uint4*)(dst + (size_t)gr * stride + ch * 4) = vls;
                }
            }
        }
        __syncthreads();
    }
}

// ---------------------------------------------------------------------------
// hist_g: per-edge rank assignment (contended device atomic) FUSED with the
// edge-logit precompute  g[h] = sum_d ea[e,d] * t[row_e, h, d].
// Outputs: rank[i] (4B) + gbuf[i] (8B), coalesced edge-order streams.
// ---------------------------------------------------------------------------
__global__ __launch_bounds__(256) void hist_g_kernel(
    const int* __restrict__ rows, const float* __restrict__ ea,
    const uint* __restrict__ tb, int* __restrict__ counts,
    int* __restrict__ rank, u32x2* __restrict__ gbuf, int e)
{
    int i = blockIdx.x * blockDim.x + threadIdx.x;
    if (i >= e) return;
    int r = rows[i];
    int rk = atomicAdd(&counts[r], 1);   // issue early; g-work hides latency

    const f32x4* ep = (const f32x4*)&ea[(size_t)i * 16];
    f32x4 e0 = __builtin_nontemporal_load(ep);
    f32x4 e1 = __builtin_nontemporal_load(ep + 1);
    f32x4 e2 = __builtin_nontemporal_load(ep + 2);
    f32x4 e3 = __builtin_nontemporal_load(ep + 3);
    const uint* tp = tb + (size_t)r * 32;
    float g[4];
    #pragma unroll
    for (int h = 0; h < 4; ++h) {
        uint4 ua = *(const uint4*)(tp + h * 8);
        uint4 ub = *(const uint4*)(tp + h * 8 + 4);
        g[h] = e0[0] * bflo(ua.x) + e0[1] * bfhi(ua.x)
             + e0[2] * bflo(ua.y) + e0[3] * bfhi(ua.y)
             + e1[0] * bflo(ua.z) + e1[1] * bfhi(ua.z)
             + e1[2] * bflo(ua.w) + e1[3] * bfhi(ua.w)
             + e2[0] * bflo(ub.x) + e2[1] * bfhi(ub.x)
             + e2[2] * bflo(ub.y) + e2[3] * bfhi(ub.y)
             + e3[0] * bflo(ub.z) + e3[1] * bfhi(ub.z)
             + e3[2] * bflo(ub.w) + e3[3] * bfhi(ub.w);
    }
    u32x2 gp;
    gp.x = (uint)f2bf(g[0]) | ((uint)f2bf(g[1]) << 16);
    gp.y = (uint)f2bf(g[2]) | ((uint)f2bf(g[3]) << 16);
    gbuf[i] = gp;
    rank[i] = rk;
}

__global__ __launch_bounds__(1024) void scan1_kernel(int* __restrict__ data,
                                                     int* __restrict__ bsum, int n)
{
    __shared__ int s[1024];
    int i = blockIdx.x * 1024 + threadIdx.x;
    int v = (i < n) ? data[i] : 0;
    s[threadIdx.x] = v;
    __syncthreads();
    for (int offd = 1; offd < 1024; offd <<= 1) {
        int add = (threadIdx.x >= offd) ? s[threadIdx.x - offd] : 0;
        __syncthreads();
        s[threadIdx.x] += add;
        __syncthreads();
    }
    if (i < n) data[i] = s[threadIdx.x];
    if (threadIdx.x == 1023) bsum[blockIdx.x] = s[1023];
}

// fused scan2+scan3: every block redoes the (cheap) 1024-wide scan of bsum
// in LDS and picks its own exclusive prefix; then emits offsets.
__global__ __launch_bounds__(1024) void scan23_kernel(const int* __restrict__ incl,
                                                      const int* __restrict__ bsum,
                                                      int* __restrict__ offsets,
                                                      int n, int nb)
{
    __shared__ int s[1024];
    int tid = threadIdx.x;
    int v = (tid < nb) ? bsum[tid] : 0;
    s[tid] = v;
    __syncthreads();
    for (int o = 1; o < 1024; o <<= 1) {
        int add = (tid >= o) ? s[tid - o] : 0;
        __syncthreads();
        s[tid] += add;
        __syncthreads();
    }
    int bofs = (blockIdx.x == 0) ? 0 : s[blockIdx.x - 1];
    int i = blockIdx.x * 1024 + tid;
    if (i == 0) offsets[0] = 0;
    if (i < n) offsets[i + 1] = incl[i] + bofs;
}

// ---------------------------------------------------------------------------
// scatter: pure permutation. Read {rows, cols, rank, gbuf} (24B coalesced)
// -> NT-store 16B CSR record {src, 0, g01, g23} at offsets[r]+rank.
// ---------------------------------------------------------------------------
__global__ __launch_bounds__(256) void scatter_kernel(
    const int* __restrict__ rows, const int* __restrict__ cols,
    const int* __restrict__ rank, const u32x2* __restrict__ gbuf,
    const int* __restrict__ offsets, i32x4* __restrict__ csr, int e)
{
    int i = blockIdx.x * blockDim.x + threadIdx.x;
    if (i >= e) return;
    int r = rows[i];
    int pos = offsets[r] + rank[i];
    u32x2 g = gbuf[i];
    i32x4 rec;
    rec.x = cols[i];
    rec.y = 0;
    rec.z = (int)g.x;
    rec.w = (int)g.y;
    __builtin_nontemporal_store(rec, &csr[pos]);
}

// ---------------------------------------------------------------------------
// Aggregation: one wave per destination node, 8 edges in flight (2x unrolled
// over 4 edge slots). lane = es*16 + h*4 + cq; lane owns channels
// c0 = h*32+cq*8 .. +8 of its slot. At the memory-service wall (~3.5 TB/s
// random-gather): MLP x2 confirmed neutral, traffic is compulsory.
// ---------------------------------------------------------------------------
__global__ __launch_bounds__(256) void agg_kernel(
    const uint* __restrict__ qb, const uint* __restrict__ kv,
    const uint* __restrict__ sb, const i32x4* __restrict__ csr,
    const int* __restrict__ offsets, const float* __restrict__ Wbeta,
    float* __restrict__ out, int n)
{
    int wid = (blockIdx.x * blockDim.x + threadIdx.x) >> 6;
    int lane = threadIdx.x & 63;
    if (wid >= n) return;
    const int es = lane >> 4;
    const int h  = (lane >> 2) & 3;
    const int cq = lane & 3;
    const int c0 = h * 32 + cq * 8;

    uint4 uq = *(const uint4*)&qb[(size_t)wid * 64 + h * 16 + cq * 4];
    float qv[8] = { bflo(uq.x), bfhi(uq.x), bflo(uq.y), bfhi(uq.y),
                    bflo(uq.z), bfhi(uq.z), bflo(uq.w), bfhi(uq.w) };

    const int beg = offsets[wid], end = offsets[wid + 1];
    const float scale = 0.17677669529663687f;  // 1/sqrt(32)

    float denom = 0.f;
    float acc[8];
    #pragma unroll
    for (int j = 0; j < 8; ++j) acc[j] = 0.f;

    for (int i = beg; i < end; i += 8) {
        int idxA = i + es;
        int idxB = i + es + 4;
        bool vA = idxA < end;
        bool vB = idxB < end;
        int cA = vA ? idxA : end - 1;
        int cB = vB ? idxB : end - 1;
        i32x4 seA = __builtin_nontemporal_load(&csr[cA]);
        i32x4 seB = __builtin_nontemporal_load(&csr[cB]);
        const uint* krA = kv + (size_t)seA.x * 128 + h * 16 + cq * 4;
        const uint* krB = kv + (size_t)seB.x * 128 + h * 16 + cq * 4;
        uint4 kpA = *(const uint4*)krA;
        uint4 vpA = *(const uint4*)(krA + 64);
        uint4 kpB = *(const uint4*)krB;
        uint4 vpB = *(const uint4*)(krB + 64);

        uint gwA = (h & 2) ? (uint)seA.w : (uint)seA.z;
        float ghA = (h & 1) ? bfhi(gwA) : bflo(gwA);
        uint gwB = (h & 2) ? (uint)seB.w : (uint)seB.z;
        float ghB = (h & 1) ? bfhi(gwB) : bflo(gwB);

        float pa = qv[0] * bflo(kpA.x) + qv[1] * bfhi(kpA.x)
                 + qv[2] * bflo(kpA.y) + qv[3] * bfhi(kpA.y)
                 + qv[4] * bflo(kpA.z) + qv[5] * bfhi(kpA.z)
                 + qv[6] * bflo(kpA.w) + qv[7] * bfhi(kpA.w);
        float pb = qv[0] * bflo(kpB.x) + qv[1] * bfhi(kpB.x)
                 + qv[2] * bflo(kpB.y) + qv[3] * bfhi(kpB.y)
                 + qv[4] * bflo(kpB.z) + qv[5] * bfhi(kpB.z)
                 + qv[6] * bflo(kpB.w) + qv[7] * bfhi(kpB.w);
        pa += __shfl_xor(pa, 1);
        pa += __shfl_xor(pa, 2);
        pb += __shfl_xor(pb, 1);
        pb += __shfl_xor(pb, 2);
        float eA = vA ? __expf((pa + ghA) * scale) : 0.f;
        float eB = vB ? __expf((pb + ghB) * scale) : 0.f;
        denom += eA + eB;
        acc[0] += eA * bflo(vpA.x) + eB * bflo(vpB.x);
        acc[1] += eA * bfhi(vpA.x) + eB * bfhi(vpB.x);
        acc[2] += eA * bflo(vpA.y) + eB * bflo(vpB.y);
        acc[3] += eA * bfhi(vpA.y) + eB * bfhi(vpB.y);
        acc[4] += eA * bflo(vpA.z) + eB * bflo(vpB.z);
        acc[5] += eA * bfhi(vpA.z) + eB * bfhi(vpB.z);
        acc[6] += eA * bflo(vpA.w) + eB * bflo(vpB.w);
        acc[7] += eA * bfhi(vpA.w) + eB * bfhi(vpB.w);
    }

    denom += __shfl_xor(denom, 16);
    denom += __shfl_xor(denom, 32);
    #pragma unroll
    for (int j = 0; j < 8; ++j) {
        acc[j] += __shfl_xor(acc[j], 16);
        acc[j] += __shfl_xor(acc[j], 32);
    }

    float inv = 1.f / (denom + 1e-16f);
    float o[8];
    #pragma unroll
    for (int j = 0; j < 8; ++j) o[j] = acc[j] * inv;

    uint4 us = *(const uint4*)&sb[(size_t)wid * 64 + h * 16 + cq * 4];
    float xsv[8] = { bflo(us.x), bfhi(us.x), bflo(us.y), bfhi(us.y),
                     bflo(us.z), bfhi(us.z), bflo(us.w), bfhi(us.w) };

    f32x4 wb0a = *(const f32x4*)&Wbeta[c0];
    f32x4 wb0b = *(const f32x4*)&Wbeta[c0 + 4];
    f32x4 wb1a = *(const f32x4*)&Wbeta[128 + c0];
    f32x4 wb1b = *(const f32x4*)&Wbeta[128 + c0 + 4];
    f32x4 wb2a = *(const f32x4*)&Wbeta[256 + c0];
    f32x4 wb2b = *(const f32x4*)&Wbeta[256 + c0 + 4];

    float bp = 0.f;
    #pragma unroll
    for (int j = 0; j < 4; ++j) {
        bp += o[j]     * wb0a[j] + xsv[j]     * wb1a[j] + (o[j]     - xsv[j])     * wb2a[j];
        bp += o[j + 4] * wb0b[j] + xsv[j + 4] * wb1b[j] + (o[j + 4] - xsv[j + 4]) * wb2b[j];
    }
    bp += __shfl_xor(bp, 1);
    bp += __shfl_xor(bp, 2);
    bp += __shfl_xor(bp, 4);
    bp += __shfl_xor(bp, 8);
    float beta = 1.f / (1.f + __expf(-bp));

    if (es == 0) {
        float r[8];
        #pragma unroll
        for (int j = 0; j < 8; ++j) r[j] = beta * xsv[j] + (1.f - beta) * o[j];
        f32x4 r0 = { r[0], r[1], r[2], r[3] };
        f32x4 r1 = { r[4], r[5], r[6], r[7] };
        __builtin_nontemporal_store(r0, (f32x4*)&out[(size_t)wid * 128 + c0]);
        __builtin_nontemporal_store(r1, (f32x4*)&out[(size_t)wid * 128 + c0 + 4]);
    }
}

// ---------------------------------------------------------------------------
extern "C" void kernel_launch(void* const* d_in, const int* in_sizes, int n_in,
                              void* d_out, int out_size, void* d_ws, size_t ws_size,
                              hipStream_t stream)
{
    const float* x     = (const float*)d_in[0];
    const float* ea    = (const float*)d_in[1];
    const int*   ei    = (const int*)d_in[2];   // [0:E)=row(dst), [E:2E)=col(src)
    const float* Wq    = (const float*)d_in[3];
    const float* bq    = (const float*)d_in[4];
    const float* Wk    = (const float*)d_in[5];
    const float* bk    = (const float*)d_in[6];
    const float* Wv    = (const float*)d_in[7];
    const float* bv    = (const float*)d_in[8];
    const float* We    = (const float*)d_in[9];
    const float* Wsk   = (const float*)d_in[10];
    const float* bsk   = (const float*)d_in[11];
    const float* Wbeta = (const float*)d_in[12];
    float* out = (float*)d_out;

    const int N = in_sizes[0] / 128;
    const int E = in_sizes[1] / 16;
    const int NT = (N + 127) / 128;         // 128-row tiles
    const int nchunks = NT * 2048;

    char* base = (char*)d_ws;
    size_t off = 0;
    auto alloc = [&](size_t bytes) -> void* {
        void* p = base + off;
        off += (bytes + 255) & ~(size_t)255;
        return p;
    };
    int*    tmp     = (int*)alloc((size_t)N * 4);
    int*    offsets = (int*)alloc((size_t)(N + 1) * 4);
    int*    bsum    = (int*)alloc(4096 * 4);
    int*    rank    = (int*)alloc((size_t)E * 4);
    u32x2*  gbuf    = (u32x2*)alloc((size_t)E * 8);
    float*  btbuf   = (float*)alloc(256);
    // xfrag is dead after lin_mfma; csr (written by scatter, later) aliases it.
    size_t  xfrag_bytes = (size_t)nchunks * 16;
    size_t  csr_bytes   = (size_t)E * 16;
    char*   shared_reg  = (char*)alloc(xfrag_bytes > csr_bytes ? xfrag_bytes : csr_bytes);
    uint4*  xfrag   = (uint4*)shared_reg;
    i32x4*  csr     = (i32x4*)shared_reg;
    uint4*  wfrag   = (uint4*)alloc((size_t)10240 * 16);  // 5 matrices
    uint*   qbuf    = (uint*)alloc((size_t)N * 64 * 4);   // bf16 pairs
    uint*   sbuf    = (uint*)alloc((size_t)N * 64 * 4);   // bf16 pairs
    uint*   tbuf    = (uint*)alloc((size_t)N * 32 * 4);   // bf16 pairs [n][h*8+d/2]
    uint*   kvbuf   = (uint*)alloc((size_t)N * 128 * 4);  // bf16: k [0..63], v [64..127]
    (void)ws_size; (void)n_in; (void)out_size;

    int prep_total = nchunks + 10240 + N;
    prep_kernel<<<(prep_total + 255) / 256, 256, 0, stream>>>(
        x, xfrag, N, nchunks, Wq, Wk, Wv, Wsk, We, bq, wfrag, btbuf, tmp);
    lin_mfma<<<NT, 256, 0, stream>>>(xfrag, wfrag, bq, bk, bv, bsk, btbuf,
                                     qbuf, kvbuf, sbuf, tbuf, N);
    hist_g_kernel<<<(E + 255) / 256, 256, 0, stream>>>(ei, ea, tbuf, tmp,
                                                       rank, gbuf, E);
    int nb = (N + 1023) / 1024;
    scan1_kernel<<<nb, 1024, 0, stream>>>(tmp, bsum, N);
    scan23_kernel<<<nb, 1024, 0, stream>>>(tmp, bsum, offsets, N, nb);
    scatter_kernel<<<(E + 255) / 256, 256, 0, stream>>>(ei, ei + E, rank, gbuf,
                                                        offsets, csr, E);
    agg_kernel<<<(N + 3) / 4, 256, 0, stream>>>(qbuf, kvbuf, sbuf, csr,
                                                offsets, Wbeta, out, N);
}